// Round 11
// baseline (415.967 us; speedup 1.0000x reference)
//
#include <hip/hip_runtime.h>
#include <hip/hip_bf16.h>

typedef __attribute__((ext_vector_type(8))) short short8v;
typedef __attribute__((ext_vector_type(4))) float f32x4;
typedef __attribute__((ext_vector_type(4))) unsigned short us4;
typedef __attribute__((ext_vector_type(4))) unsigned u32x4;

#define DEV static __device__ __forceinline__

DEV unsigned short f2bf(float f) {
  unsigned u = __builtin_bit_cast(unsigned, f);
  u += 0x7FFFu + ((u >> 16) & 1u);
  return (unsigned short)(u >> 16);
}
DEV float bf2f(unsigned short s) {
  unsigned u = ((unsigned)s) << 16;
  return __builtin_bit_cast(float, u);
}
DEV void gload16(const void* g, void* l) {
  __builtin_amdgcn_global_load_lds((const __attribute__((address_space(1))) void*)g,
                                   (__attribute__((address_space(3))) void*)l, 16, 0, 0);
}

// ============ fused prep: cvt(wqkv) | cvt(wout) | pmprep | ropetab | rms ============
__global__ __launch_bounds__(256) void k_prep(const float* __restrict__ w_qkv,
                                              unsigned short* __restrict__ wqkvb,
                                              const float* __restrict__ w_out,
                                              unsigned short* __restrict__ woutb,
                                              const float* __restrict__ pm,
                                              unsigned short* __restrict__ pmk,
                                              unsigned short* __restrict__ vt,
                                              unsigned short* __restrict__ zbuf,
                                              float* __restrict__ ct,
                                              float* __restrict__ st,
                                              const float* __restrict__ x,
                                              const float* __restrict__ norm_w,
                                              unsigned short* __restrict__ xb) {
  __shared__ float red[4];
  const int b = blockIdx.x, tid = threadIdx.x;
  if (b < 12288) {
    long i = (long)b * 256 + tid;
    f32x4 v = *((const f32x4*)w_qkv + i);
    us4 o;
    o[0] = f2bf(v[0]); o[1] = f2bf(v[1]); o[2] = f2bf(v[2]); o[3] = f2bf(v[3]);
    *((us4*)wqkvb + i) = o;
  } else if (b < 16384) {
    long i = (long)(b - 12288) * 256 + tid;
    f32x4 v = *((const f32x4*)w_out + i);
    us4 o;
    o[0] = f2bf(v[0]); o[1] = f2bf(v[1]); o[2] = f2bf(v[2]); o[3] = f2bf(v[3]);
    *((us4*)woutb + i) = o;
  } else if (b < 16512) {
    int idx = (b - 16384) * 256 + tid;
    if (idx < 8) zbuf[idx] = 0;
    int d = idx & 127, p = (idx >> 7) & 15, h = idx >> 11;
    float kvl = pm[((0 * 16 + h) * 16 + p) * 128 + d];
    float vvl = pm[((1 * 16 + h) * 16 + p) * 128 + d];
    pmk[(h * 16 + p) * 128 + d] = f2bf(kvl);
    unsigned short vb = f2bf(vvl);
    for (int w = 0; w < 16; ++w) {
      long base = ((long)(w * 16 + h) * 128 + d) * 576;
      vt[base + p] = vb;
      vt[base + 528 + p] = 0;
      vt[base + 544 + p] = 0;
      vt[base + 560 + p] = 0;
    }
  } else if (b < 17536) {
    int idx = (b - 16512) * 256 + tid;  // 262144
    int pos = idx >> 6, i = idx & 63;
    float invf = __powf(10000.f, -(float)i * (1.f / 64.f));
    float a = (float)pos * invf;
    ct[idx] = cosf(a);
    st[idx] = sinf(a);
  } else {
    int row = b - 17536;
    const f32x4* xr = (const f32x4*)(x + (long)row * 2048);
    f32x4 v0 = xr[tid * 2], v1 = xr[tid * 2 + 1];
    float ss = v0[0]*v0[0] + v0[1]*v0[1] + v0[2]*v0[2] + v0[3]*v0[3]
             + v1[0]*v1[0] + v1[1]*v1[1] + v1[2]*v1[2] + v1[3]*v1[3];
    ss += __shfl_xor(ss, 1);  ss += __shfl_xor(ss, 2);  ss += __shfl_xor(ss, 4);
    ss += __shfl_xor(ss, 8);  ss += __shfl_xor(ss, 16); ss += __shfl_xor(ss, 32);
    if ((tid & 63) == 0) red[tid >> 6] = ss;
    __syncthreads();
    float tot = red[0] + red[1] + red[2] + red[3];
    float rs = rsqrtf(tot * (1.f / 2048.f) + 1e-6f);
    float xv[8] = {v0[0], v0[1], v0[2], v0[3], v1[0], v1[1], v1[2], v1[3]};
    short8v pack;
#pragma unroll
    for (int j = 0; j < 8; ++j) pack[j] = (short)f2bf(xv[j] * rs * norm_w[tid * 8 + j]);
    *((short8v*)(xb + (long)row * 2048) + tid) = pack;
  }
}

// ================= 256x256 8-phase bf16 GEMM: C[M,N] = A[M,K] * B[N,K]^T =================
// R2-exact staging schedule (R10's A-both-at-ph1 regressed; reverted).

#define VMCNT4 asm volatile("s_waitcnt vmcnt(4)" ::: "memory")
#define VMCNT0 asm volatile("s_waitcnt vmcnt(0)" ::: "memory")
#define SCHEDB __builtin_amdgcn_sched_barrier(0)
#define NOSTG ((void)0)

template <int OUTF32>
__global__ __launch_bounds__(512, 2) void k_gemm8(const unsigned short* __restrict__ A,
                                                  const unsigned short* __restrict__ B,
                                                  unsigned short* __restrict__ Cb,
                                                  float* __restrict__ Cf,
                                                  int M, int N, int K) {
  __shared__ __align__(16) unsigned short lds[4 * 256 * 64];  // buf0:A,B buf1:A,B (32KB each)
  const int tid = threadIdx.x;
  const int lane = tid & 63;
  const int ql = lane & 15, g = lane >> 4;
  const int wid = tid >> 6;
  const int wm = wid >> 2, wn = wid & 3;

  const int nbx = N >> 8;
  const int nwg = gridDim.x;
  int bid = blockIdx.x;
  int swz = (bid & 7) * (nwg >> 3) + (bid >> 3);
  int by = swz / nbx, bx = swz - by * nbx;
  const long rowA0 = (long)by << 8;
  const long rowB0 = (long)bx << 8;

  const int idx0 = tid, idx1 = 512 + tid;
  const int dr0 = idx0 >> 3, sc0 = (idx0 & 7) ^ (dr0 & 7);
  const int dr1 = idx1 >> 3, sc1 = (idx1 & 7) ^ (dr1 & 7);
  const long halfA = 128L * K;
  const unsigned short* pA0 = A + (rowA0 + dr0) * (long)K + sc0 * 8;
  const unsigned short* pA1 = A + (rowA0 + dr1) * (long)K + sc1 * 8;
  const unsigned short* pB0 = B + (rowB0 + dr0) * (long)K + sc0 * 8;
  const unsigned short* pB1 = B + (rowB0 + dr1) * (long)K + sc1 * 8;

  const int rsw0 = (g ^ (ql & 7)) * 8;
  const int rsw1 = ((4 + g) ^ (ql & 7)) * 8;

  short8v fa[4], fb[2][4];
  f32x4 acc[8][4] = {};

#define STAGE_A(b, h, kk) do { \
  gload16(pA0 + (long)(h) * halfA + (kk), lds + (b) * 32768 + (h) * 8192 + (idx0 << 3)); \
  gload16(pA1 + (long)(h) * halfA + (kk), lds + (b) * 32768 + (h) * 8192 + (idx1 << 3)); } while (0)
#define STAGE_B(b, h, kk) do { \
  gload16(pB0 + (long)(h) * halfA + (kk), lds + (b) * 32768 + 16384 + (h) * 8192 + (idx0 << 3)); \
  gload16(pB1 + (long)(h) * halfA + (kk), lds + (b) * 32768 + 16384 + (h) * 8192 + (idx1 << 3)); } while (0)

#define PHASE(buf, mh, ks, LOADB, STG, VMC) do { \
  { const unsigned short* p_ = lds + (buf) * 32768 + (((wm << 7) + (mh) * 64 + ql) << 6) + ((ks) ? rsw1 : rsw0); \
    _Pragma("unroll") for (int mi_ = 0; mi_ < 4; ++mi_) fa[mi_] = *(const short8v*)(p_ + (mi_ << 10)); } \
  if (LOADB) { const unsigned short* p_ = lds + (buf) * 32768 + 16384 + (((wn << 6) + ql) << 6) + ((ks) ? rsw1 : rsw0); \
    _Pragma("unroll") for (int n_ = 0; n_ < 4; ++n_) fb[ks][n_] = *(const short8v*)(p_ + (n_ << 10)); } \
  STG; \
  SCHEDB; __builtin_amdgcn_s_barrier(); SCHEDB; \
  __builtin_amdgcn_s_setprio(1); \
  _Pragma("unroll") for (int mi_ = 0; mi_ < 4; ++mi_) \
    _Pragma("unroll") for (int n_ = 0; n_ < 4; ++n_) \
      acc[(mh) * 4 + mi_][n_] = __builtin_amdgcn_mfma_f32_16x16x32_bf16(fa[mi_], fb[ks][n_], acc[(mh) * 4 + mi_][n_], 0, 0, 0); \
  __builtin_amdgcn_s_setprio(0); \
  VMC; \
  SCHEDB; __builtin_amdgcn_s_barrier(); SCHEDB; \
} while (0)

  const int NT = K >> 6;
  const int NITER = NT >> 1;

  STAGE_A(0, 0, 0); STAGE_A(0, 1, 0);
  STAGE_B(0, 0, 0); STAGE_B(0, 1, 0);
  STAGE_B(1, 0, 64); STAGE_B(1, 1, 64);
  VMCNT4;
  SCHEDB; __builtin_amdgcn_s_barrier(); SCHEDB;

  for (int i = 0; i < NITER - 1; ++i) {
    const int k1 = (2 * i + 1) << 6;
    const int k2 = (2 * i + 2) << 6;
    const int k3 = (2 * i + 3) << 6;
    PHASE(0, 0, 0, 1, STAGE_A(1, 0, k1), NOSTG);
    PHASE(0, 0, 1, 1, STAGE_A(1, 1, k1), NOSTG);
    PHASE(0, 1, 0, 0, STAGE_B(0, 0, k2), NOSTG);
    PHASE(0, 1, 1, 0, STAGE_B(0, 1, k2), VMCNT4);
    PHASE(1, 0, 0, 1, STAGE_A(0, 0, k2), NOSTG);
    PHASE(1, 0, 1, 1, STAGE_A(0, 1, k2), NOSTG);
    PHASE(1, 1, 0, 0, STAGE_B(1, 0, k3), NOSTG);
    PHASE(1, 1, 1, 0, STAGE_B(1, 1, k3), VMCNT4);
  }
  {
    const int k1 = (NT - 1) << 6;
    PHASE(0, 0, 0, 1, STAGE_A(1, 0, k1), NOSTG);
    PHASE(0, 0, 1, 1, STAGE_A(1, 1, k1), NOSTG);
    PHASE(0, 1, 0, 0, NOSTG, NOSTG);
    PHASE(0, 1, 1, 0, NOSTG, VMCNT0);
    PHASE(1, 0, 0, 1, NOSTG, NOSTG);
    PHASE(1, 0, 1, 1, NOSTG, NOSTG);
    PHASE(1, 1, 0, 0, NOSTG, NOSTG);
    PHASE(1, 1, 1, 0, NOSTG, NOSTG);
  }

#pragma unroll
  for (int am = 0; am < 8; ++am)
#pragma unroll
    for (int n = 0; n < 4; ++n)
#pragma unroll
      for (int r = 0; r < 4; ++r) {
        long row = rowA0 + (wm << 7) + am * 16 + (g << 2) + r;
        long col = rowB0 + (wn << 6) + n * 16 + ql;
        if (OUTF32) Cf[row * N + col] = acc[am][n][r];
        else        Cb[row * N + col] = f2bf(acc[am][n][r]);
      }
#undef STAGE_A
#undef STAGE_B
#undef PHASE
}

// ---------------- fused K-RoPE (in-place) + V transpose -> vt ----------------
__global__ __launch_bounds__(256) void k_kprep(unsigned short* __restrict__ qkv,
                                               unsigned short* __restrict__ vt,
                                               const float* __restrict__ ct,
                                               const float* __restrict__ st) {
  __shared__ unsigned short lt[64 * 136];
  const int tile = blockIdx.x, h = blockIdx.y;
  const int tid = threadIdx.x;
  const int t0 = tile * 64;
  {
    int row = t0 + (tid >> 2);
    int d0 = (tid & 3) * 32;
    int pos = row & 4095;
    unsigned short* kp = qkv + (long)row * 6144 + 2048 + h * 128 + d0;
    const float* cp = ct + pos * 64 + (d0 >> 1);
    const float* sp = st + pos * 64 + (d0 >> 1);
    f32x4 cv[4], sv[4];
#pragma unroll
    for (int j = 0; j < 4; ++j) { cv[j] = *(const f32x4*)(cp + j * 4); sv[j] = *(const f32x4*)(sp + j * 4); }
    short8v kv[4];
#pragma unroll
    for (int j = 0; j < 4; ++j) kv[j] = *(const short8v*)(kp + j * 8);
#pragma unroll
    for (int j = 0; j < 4; ++j) {
      short8v outv;
#pragma unroll
      for (int p = 0; p < 4; ++p) {
        float a = bf2f((unsigned short)kv[j][2 * p]);
        float b = bf2f((unsigned short)kv[j][2 * p + 1]);
        float c = cv[j][p], s = sv[j][p];
        outv[2 * p]     = (short)f2bf(a * c - b * s);
        outv[2 * p + 1] = (short)f2bf(b * c + a * s);
      }
      *(short8v*)(kp + j * 8) = outv;
    }
  }
  {
    int row = tid >> 2, seg = tid & 3;
    const unsigned short* src = qkv + (long)(t0 + row) * 6144 + 4096 + h * 128 + seg * 32;
#pragma unroll
    for (int j = 0; j < 4; ++j)
      *(short8v*)(lt + row * 136 + seg * 32 + j * 8) = *(const short8v*)(src + j * 8);
  }
  __syncthreads();
  int d = tid >> 1, half = tid & 1;
  int wh = t0 >> 9;
  long dst = ((long)(wh * 16 + h) * 128 + d) * 576 + (t0 & 511) + 16 + half * 32;
  unsigned short tmp[32];
#pragma unroll
  for (int kk = 0; kk < 32; ++kk) tmp[kk] = lt[(half * 32 + kk) * 136 + d];
#pragma unroll
  for (int j = 0; j < 4; ++j) {
    short8v v;
#pragma unroll
    for (int e = 0; e < 8; ++e) v[e] = (short)tmp[j * 8 + e];
    *(short8v*)(vt + dst + j * 8) = v;
  }
}

// ---------------- windowed attention: 256 queries/block (2 chunks/wave), KVBLK=32 ------
// grid: (wh=16, h=16, z=2). Each block stages each K/V tile ONCE for 256 queries —
// per-(wh,h) tile-stagings drop 44 -> 30 (L2->LDS was the bound). Chunks c=0,1 computed
// sequentially per tile sharing temporaries. XCD/CU balance: ids b,b+256 = z=0/1 pair.
__global__ __launch_bounds__(512) void k_attn(const unsigned short* __restrict__ qkv,
                                              const unsigned short* __restrict__ vt,
                                              const unsigned short* __restrict__ pmk,
                                              const unsigned short* __restrict__ zbuf,
                                              const float* __restrict__ ct,
                                              const float* __restrict__ stt,
                                              unsigned short* __restrict__ attno) {
  __shared__ __align__(16) unsigned short Ks[2][32 * 128];  // [key][d], src-swizzled
  __shared__ __align__(16) unsigned short Vs[2][128 * 32];  // [d][key], src-swizzled
  __shared__ unsigned Ps[8][16][16];                        // per-wave P^T strip (bf16 pairs)
  const int wh = blockIdx.x, h = blockIdx.y, z = blockIdx.z;
  const int tid = threadIdx.x;
  const int wave = tid >> 6, lane = tid & 63;
  const int ql = lane & 15, g = lane >> 4;
  const int tokbase = (wh >> 3) * 4096 + (wh & 7) * 512;
  // chunk c queries: qi_c = z*256 + c*128 + wave*16 + ql
  const int q0 = z * 256 + wave * 16 + ql;
  short8v qf[2][4];
#pragma unroll
  for (int c = 0; c < 2; ++c) {
    const int qi = q0 + c * 128;
    const long qrow = (long)(tokbase + qi) * 6144;
    const int pos = (tokbase + qi) & 4095;
#pragma unroll
    for (int ks = 0; ks < 4; ++ks) {
      short8v qv = *(const short8v*)(qkv + qrow + h * 128 + ks * 32 + g * 8);
      f32x4 cv = *(const f32x4*)(ct + pos * 64 + ks * 16 + g * 4);
      f32x4 sv = *(const f32x4*)(stt + pos * 64 + ks * 16 + g * 4);
      const float SC = 0.08838834764831845f;
#pragma unroll
      for (int p = 0; p < 4; ++p) {
        float a = bf2f((unsigned short)qv[2 * p]);
        float b = bf2f((unsigned short)qv[2 * p + 1]);
        qf[c][ks][2 * p]     = (short)f2bf((a * cv[p] - b * sv[p]) * SC);
        qf[c][ks][2 * p + 1] = (short)f2bf((b * cv[p] + a * sv[p]) * SC);
      }
    }
  }
  const int nkt = min(17, (z * 256 + 256 + 144 + 31) >> 5);  // 13 or 17
  const long vbase = (long)(wh * 16 + h) * 128 * 576;

  float mrun[2] = {-3.0e38f, -3.0e38f}, lrun[2] = {0.f, 0.f};
  f32x4 o[2][8] = {};

#define STAGEKV(kt, b) do { \
    { int kl_ = tid >> 4, dc_ = tid & 15, dcs_ = dc_ ^ (kl_ & 7); \
      int ki_ = (kt) * 32 + kl_; \
      const unsigned short* src_; \
      if (ki_ < 16)       src_ = pmk + (h * 16 + ki_) * 128 + dcs_ * 8; \
      else if (ki_ < 528) src_ = qkv + (long)(tokbase + ki_ - 16) * 6144 + 2048 + h * 128 + dcs_ * 8; \
      else                src_ = zbuf; \
      gload16(src_, &Ks[b][0] + (size_t)tid * 8); } \
    { int d_ = tid >> 2, kc_ = tid & 3, kcs_ = kc_ ^ (d_ & 3); \
      gload16(vt + vbase + (long)d_ * 576 + (kt) * 32 + kcs_ * 8, &Vs[b][0] + (size_t)tid * 8); } \
  } while (0)

  STAGEKV(0, 0);
  __syncthreads();
  for (int kt = 0; kt < nkt; ++kt) {
    const int cur = kt & 1;
    if (kt + 1 < nkt) STAGEKV(kt + 1, cur ^ 1);
#pragma unroll
    for (int c = 0; c < 2; ++c) {
      const int qi = q0 + c * 128;
      const int wqmin = z * 256 + c * 128 + wave * 16;
      if (kt * 32 > wqmin + 15 + 16) continue;  // fully-masked for this chunk
      f32x4 stv[2] = {};
      __builtin_amdgcn_s_setprio(1);
#pragma unroll
      for (int kf = 0; kf < 2; ++kf) {
        int row = kf * 16 + ql;
#pragma unroll
        for (int ks = 0; ks < 4; ++ks) {
          int chunk = (ks * 4 + g) ^ (row & 7);
          short8v kv = *(const short8v*)(&Ks[cur][0] + row * 128 + chunk * 8);
          stv[kf] = __builtin_amdgcn_mfma_f32_16x16x32_bf16(kv, qf[c][ks], stv[kf], 0, 0, 0);
        }
      }
      __builtin_amdgcn_s_setprio(0);
      float tmax = -3.0e38f;
      const bool needmask = !(kt == 0 || (kt * 32 + 15 <= wqmin));
      if (needmask) {
#pragma unroll
        for (int kf = 0; kf < 2; ++kf)
#pragma unroll
          for (int r = 0; r < 4; ++r) {
            int ki = kt * 32 + kf * 16 + g * 4 + r;
            bool ok = (ki < 32) || (qi >= 16 && ki <= qi + 16);
            float s = ok ? stv[kf][r] : -3.0e38f;
            stv[kf][r] = s;
            tmax = fmaxf(tmax, s);
          }
      } else {
#pragma unroll
        for (int kf = 0; kf < 2; ++kf)
#pragma unroll
          for (int r = 0; r < 4; ++r) tmax = fmaxf(tmax, stv[kf][r]);
      }
      tmax = fmaxf(tmax, __shfl_xor(tmax, 16));
      tmax = fmaxf(tmax, __shfl_xor(tmax, 32));
      if (!__all(tmax <= mrun[c] + 8.f)) {
        float mnew = fmaxf(mrun[c], tmax);
        float corr = __expf(mrun[c] - mnew);
        lrun[c] *= corr;
#pragma unroll
        for (int db = 0; db < 8; ++db) {
          o[c][db][0] *= corr; o[c][db][1] *= corr;
          o[c][db][2] *= corr; o[c][db][3] *= corr;
        }
        mrun[c] = mnew;
      }
#pragma unroll
      for (int kf = 0; kf < 2; ++kf)
#pragma unroll
        for (int r = 0; r < 4; ++r) {
          float p = __expf(stv[kf][r] - mrun[c]);
          stv[kf][r] = p;
          lrun[c] += p;
        }
      // P^T -> bf16 pairs -> wave-local LDS strip -> B-fragment
#pragma unroll
      for (int kf = 0; kf < 2; ++kf) {
        unsigned w01 = (unsigned)f2bf(stv[kf][0]) | ((unsigned)f2bf(stv[kf][1]) << 16);
        unsigned w23 = (unsigned)f2bf(stv[kf][2]) | ((unsigned)f2bf(stv[kf][3]) << 16);
        int pr = kf * 8 + 2 * g;
        Ps[wave][pr][ql ^ (pr & 7)] = w01;
        Ps[wave][pr + 1][ql ^ ((pr + 1) & 7)] = w23;
      }
      u32x4 pbw;
#pragma unroll
      for (int t = 0; t < 4; ++t) {
        int pr = 4 * g + t;
        pbw[t] = Ps[wave][pr][ql ^ (pr & 7)];
      }
      short8v pb = __builtin_bit_cast(short8v, pbw);
      __builtin_amdgcn_s_setprio(1);
#pragma unroll
      for (int db = 0; db < 8; ++db) {
        int d = db * 16 + ql;
        int kc = g ^ (d & 3);
        short8v vf = *(const short8v*)(&Vs[cur][0] + d * 32 + kc * 8);
        o[c][db] = __builtin_amdgcn_mfma_f32_16x16x32_bf16(vf, pb, o[c][db], 0, 0, 0);
      }
      __builtin_amdgcn_s_setprio(0);
    }
    __syncthreads();
  }
#undef STAGEKV
#pragma unroll
  for (int c = 0; c < 2; ++c) {
    float l = lrun[c];
    l += __shfl_xor(l, 16);
    l += __shfl_xor(l, 32);
    float inv = 1.0f / l;
    long obase = (long)(tokbase + q0 + c * 128) * 2048 + h * 128;
#pragma unroll
    for (int db = 0; db < 8; ++db) {
      us4 ov;
#pragma unroll
      for (int r = 0; r < 4; ++r) ov[r] = f2bf(o[c][db][r] * inv);
      *(us4*)(attno + obase + db * 16 + g * 4) = ov;
    }
  }
}

extern "C" void kernel_launch(void* const* d_in, const int* in_sizes, int n_in,
                              void* d_out, int out_size, void* d_ws, size_t ws_size,
                              hipStream_t stream) {
  const float* x      = (const float*)d_in[0];
  const float* norm_w = (const float*)d_in[1];
  const float* w_qkv  = (const float*)d_in[2];
  const float* w_out  = (const float*)d_in[3];
  const float* pm     = (const float*)d_in[4];
  float* out = (float*)d_out;

  char* ws = (char*)d_ws;
  size_t off = 0;
  auto alloc = [&](size_t bytes) -> void* {
    void* p = ws + off;
    off += (bytes + 255) & ~(size_t)255;
    return p;
  };
  unsigned short* xb    = (unsigned short*)alloc(8192ull * 2048 * 2);
  unsigned short* wqkvb = (unsigned short*)alloc(6144ull * 2048 * 2);
  unsigned short* woutb = (unsigned short*)alloc(2048ull * 2048 * 2);
  unsigned short* qkv   = (unsigned short*)alloc(8192ull * 6144 * 2);
  unsigned short* vt    = (unsigned short*)alloc(256ull * 128 * 576 * 2);
  unsigned short* attno = (unsigned short*)alloc(8192ull * 2048 * 2);
  unsigned short* pmk   = (unsigned short*)alloc(16 * 16 * 128 * 2);
  float* ct             = (float*)alloc(4096 * 64 * 4);
  float* stt            = (float*)alloc(4096 * 64 * 4);
  unsigned short* zbuf  = (unsigned short*)alloc(256);

  hipLaunchKernelGGL(k_prep, dim3(25728), dim3(256), 0, stream,
                     w_qkv, wqkvb, w_out, woutb, pm, pmk, vt, zbuf, ct, stt, x, norm_w, xb);
  hipLaunchKernelGGL((k_gemm8<0>), dim3(24 * 32), dim3(512), 0, stream,
                     xb, wqkvb, qkv, (float*)nullptr, 8192, 6144, 2048);
  hipLaunchKernelGGL(k_kprep, dim3(128, 16), dim3(256), 0, stream, qkv, vt, ct, stt);
  hipLaunchKernelGGL(k_attn, dim3(16, 16, 2), dim3(512), 0, stream,
                     qkv, vt, pmk, zbuf, ct, stt, attno);
  hipLaunchKernelGGL((k_gemm8<1>), dim3(8 * 32), dim3(512), 0, stream,
                     attno, woutb, (unsigned short*)nullptr, out, 8192, 2048, 2048);
}

// Round 12
// 401.950 us; speedup vs baseline: 1.0349x; 1.0349x over previous
//
#include <hip/hip_runtime.h>
#include <hip/hip_bf16.h>

typedef __attribute__((ext_vector_type(8))) short short8v;
typedef __attribute__((ext_vector_type(4))) float f32x4;
typedef __attribute__((ext_vector_type(4))) unsigned short us4;
typedef __attribute__((ext_vector_type(4))) unsigned u32x4;

#define DEV static __device__ __forceinline__

DEV unsigned short f2bf(float f) {
  unsigned u = __builtin_bit_cast(unsigned, f);
  u += 0x7FFFu + ((u >> 16) & 1u);
  return (unsigned short)(u >> 16);
}
DEV float bf2f(unsigned short s) {
  unsigned u = ((unsigned)s) << 16;
  return __builtin_bit_cast(float, u);
}
DEV void gload16(const void* g, void* l) {
  __builtin_amdgcn_global_load_lds((const __attribute__((address_space(1))) void*)g,
                                   (__attribute__((address_space(3))) void*)l, 16, 0, 0);
}

// ============ fused prep: cvt(wqkv) | cvt(wout) | pmprep | ropetab | rms ============
__global__ __launch_bounds__(256) void k_prep(const float* __restrict__ w_qkv,
                                              unsigned short* __restrict__ wqkvb,
                                              const float* __restrict__ w_out,
                                              unsigned short* __restrict__ woutb,
                                              const float* __restrict__ pm,
                                              unsigned short* __restrict__ pmk,
                                              unsigned short* __restrict__ vt,
                                              unsigned short* __restrict__ zbuf,
                                              float* __restrict__ ct,
                                              float* __restrict__ st,
                                              const float* __restrict__ x,
                                              const float* __restrict__ norm_w,
                                              unsigned short* __restrict__ xb) {
  __shared__ float red[4];
  const int b = blockIdx.x, tid = threadIdx.x;
  if (b < 12288) {
    long i = (long)b * 256 + tid;
    f32x4 v = *((const f32x4*)w_qkv + i);
    us4 o;
    o[0] = f2bf(v[0]); o[1] = f2bf(v[1]); o[2] = f2bf(v[2]); o[3] = f2bf(v[3]);
    *((us4*)wqkvb + i) = o;
  } else if (b < 16384) {
    long i = (long)(b - 12288) * 256 + tid;
    f32x4 v = *((const f32x4*)w_out + i);
    us4 o;
    o[0] = f2bf(v[0]); o[1] = f2bf(v[1]); o[2] = f2bf(v[2]); o[3] = f2bf(v[3]);
    *((us4*)woutb + i) = o;
  } else if (b < 16512) {
    int idx = (b - 16384) * 256 + tid;
    if (idx < 8) zbuf[idx] = 0;
    int d = idx & 127, p = (idx >> 7) & 15, h = idx >> 11;
    float kvl = pm[((0 * 16 + h) * 16 + p) * 128 + d];
    float vvl = pm[((1 * 16 + h) * 16 + p) * 128 + d];
    pmk[(h * 16 + p) * 128 + d] = f2bf(kvl);
    unsigned short vb = f2bf(vvl);
    for (int w = 0; w < 16; ++w) {
      long base = ((long)(w * 16 + h) * 128 + d) * 576;
      vt[base + p] = vb;
      vt[base + 528 + p] = 0;
      vt[base + 544 + p] = 0;
      vt[base + 560 + p] = 0;
    }
  } else if (b < 17536) {
    int idx = (b - 16512) * 256 + tid;  // 262144
    int pos = idx >> 6, i = idx & 63;
    float invf = __powf(10000.f, -(float)i * (1.f / 64.f));
    float a = (float)pos * invf;
    ct[idx] = cosf(a);
    st[idx] = sinf(a);
  } else {
    int row = b - 17536;
    const f32x4* xr = (const f32x4*)(x + (long)row * 2048);
    f32x4 v0 = xr[tid * 2], v1 = xr[tid * 2 + 1];
    float ss = v0[0]*v0[0] + v0[1]*v0[1] + v0[2]*v0[2] + v0[3]*v0[3]
             + v1[0]*v1[0] + v1[1]*v1[1] + v1[2]*v1[2] + v1[3]*v1[3];
    ss += __shfl_xor(ss, 1);  ss += __shfl_xor(ss, 2);  ss += __shfl_xor(ss, 4);
    ss += __shfl_xor(ss, 8);  ss += __shfl_xor(ss, 16); ss += __shfl_xor(ss, 32);
    if ((tid & 63) == 0) red[tid >> 6] = ss;
    __syncthreads();
    float tot = red[0] + red[1] + red[2] + red[3];
    float rs = rsqrtf(tot * (1.f / 2048.f) + 1e-6f);
    float xv[8] = {v0[0], v0[1], v0[2], v0[3], v1[0], v1[1], v1[2], v1[3]};
    short8v pack;
#pragma unroll
    for (int j = 0; j < 8; ++j) pack[j] = (short)f2bf(xv[j] * rs * norm_w[tid * 8 + j]);
    *((short8v*)(xb + (long)row * 2048) + tid) = pack;
  }
}

// ================= 256x256 8-phase bf16 GEMM: C[M,N] = A[M,K] * B[N,K]^T =================
// R2-exact staging schedule (proven 1085 TF, 0 bank conflicts).

#define VMCNT4 asm volatile("s_waitcnt vmcnt(4)" ::: "memory")
#define VMCNT2 asm volatile("s_waitcnt vmcnt(2)" ::: "memory")
#define VMCNT0 asm volatile("s_waitcnt vmcnt(0)" ::: "memory")
#define SCHEDB __builtin_amdgcn_sched_barrier(0)
#define NOSTG ((void)0)

template <int OUTF32>
__global__ __launch_bounds__(512, 2) void k_gemm8(const unsigned short* __restrict__ A,
                                                  const unsigned short* __restrict__ B,
                                                  unsigned short* __restrict__ Cb,
                                                  float* __restrict__ Cf,
                                                  int M, int N, int K) {
  __shared__ __align__(16) unsigned short lds[4 * 256 * 64];  // buf0:A,B buf1:A,B (32KB each)
  const int tid = threadIdx.x;
  const int lane = tid & 63;
  const int ql = lane & 15, g = lane >> 4;
  const int wid = tid >> 6;
  const int wm = wid >> 2, wn = wid & 3;

  const int nbx = N >> 8;
  const int nwg = gridDim.x;
  int bid = blockIdx.x;
  int swz = (bid & 7) * (nwg >> 3) + (bid >> 3);
  int by = swz / nbx, bx = swz - by * nbx;
  const long rowA0 = (long)by << 8;
  const long rowB0 = (long)bx << 8;

  const int idx0 = tid, idx1 = 512 + tid;
  const int dr0 = idx0 >> 3, sc0 = (idx0 & 7) ^ (dr0 & 7);
  const int dr1 = idx1 >> 3, sc1 = (idx1 & 7) ^ (dr1 & 7);
  const long halfA = 128L * K;
  const unsigned short* pA0 = A + (rowA0 + dr0) * (long)K + sc0 * 8;
  const unsigned short* pA1 = A + (rowA0 + dr1) * (long)K + sc1 * 8;
  const unsigned short* pB0 = B + (rowB0 + dr0) * (long)K + sc0 * 8;
  const unsigned short* pB1 = B + (rowB0 + dr1) * (long)K + sc1 * 8;

  const int rsw0 = (g ^ (ql & 7)) * 8;
  const int rsw1 = ((4 + g) ^ (ql & 7)) * 8;

  short8v fa[4], fb[2][4];
  f32x4 acc[8][4] = {};

#define STAGE_A(b, h, kk) do { \
  gload16(pA0 + (long)(h) * halfA + (kk), lds + (b) * 32768 + (h) * 8192 + (idx0 << 3)); \
  gload16(pA1 + (long)(h) * halfA + (kk), lds + (b) * 32768 + (h) * 8192 + (idx1 << 3)); } while (0)
#define STAGE_B(b, h, kk) do { \
  gload16(pB0 + (long)(h) * halfA + (kk), lds + (b) * 32768 + 16384 + (h) * 8192 + (idx0 << 3)); \
  gload16(pB1 + (long)(h) * halfA + (kk), lds + (b) * 32768 + 16384 + (h) * 8192 + (idx1 << 3)); } while (0)

#define PHASE(buf, mh, ks, LOADB, STG, VMC) do { \
  { const unsigned short* p_ = lds + (buf) * 32768 + (((wm << 7) + (mh) * 64 + ql) << 6) + ((ks) ? rsw1 : rsw0); \
    _Pragma("unroll") for (int mi_ = 0; mi_ < 4; ++mi_) fa[mi_] = *(const short8v*)(p_ + (mi_ << 10)); } \
  if (LOADB) { const unsigned short* p_ = lds + (buf) * 32768 + 16384 + (((wn << 6) + ql) << 6) + ((ks) ? rsw1 : rsw0); \
    _Pragma("unroll") for (int n_ = 0; n_ < 4; ++n_) fb[ks][n_] = *(const short8v*)(p_ + (n_ << 10)); } \
  STG; \
  SCHEDB; __builtin_amdgcn_s_barrier(); SCHEDB; \
  __builtin_amdgcn_s_setprio(1); \
  _Pragma("unroll") for (int mi_ = 0; mi_ < 4; ++mi_) \
    _Pragma("unroll") for (int n_ = 0; n_ < 4; ++n_) \
      acc[(mh) * 4 + mi_][n_] = __builtin_amdgcn_mfma_f32_16x16x32_bf16(fa[mi_], fb[ks][n_], acc[(mh) * 4 + mi_][n_], 0, 0, 0); \
  __builtin_amdgcn_s_setprio(0); \
  VMC; \
  SCHEDB; __builtin_amdgcn_s_barrier(); SCHEDB; \
} while (0)

  const int NT = K >> 6;
  const int NITER = NT >> 1;

  STAGE_A(0, 0, 0); STAGE_A(0, 1, 0);
  STAGE_B(0, 0, 0); STAGE_B(0, 1, 0);
  STAGE_B(1, 0, 64); STAGE_B(1, 1, 64);
  VMCNT4;
  SCHEDB; __builtin_amdgcn_s_barrier(); SCHEDB;

  for (int i = 0; i < NITER - 1; ++i) {
    const int k1 = (2 * i + 1) << 6;
    const int k2 = (2 * i + 2) << 6;
    const int k3 = (2 * i + 3) << 6;
    PHASE(0, 0, 0, 1, STAGE_A(1, 0, k1), NOSTG);
    PHASE(0, 0, 1, 1, STAGE_A(1, 1, k1), NOSTG);
    PHASE(0, 1, 0, 0, STAGE_B(0, 0, k2), NOSTG);
    PHASE(0, 1, 1, 0, STAGE_B(0, 1, k2), VMCNT4);
    PHASE(1, 0, 0, 1, STAGE_A(0, 0, k2), NOSTG);
    PHASE(1, 0, 1, 1, STAGE_A(0, 1, k2), NOSTG);
    PHASE(1, 1, 0, 0, STAGE_B(1, 0, k3), NOSTG);
    PHASE(1, 1, 1, 0, STAGE_B(1, 1, k3), VMCNT4);
  }
  {
    const int k1 = (NT - 1) << 6;
    PHASE(0, 0, 0, 1, STAGE_A(1, 0, k1), NOSTG);
    PHASE(0, 0, 1, 1, STAGE_A(1, 1, k1), NOSTG);
    PHASE(0, 1, 0, 0, NOSTG, NOSTG);
    PHASE(0, 1, 1, 0, NOSTG, VMCNT0);
    PHASE(1, 0, 0, 1, NOSTG, NOSTG);
    PHASE(1, 0, 1, 1, NOSTG, NOSTG);
    PHASE(1, 1, 0, 0, NOSTG, NOSTG);
    PHASE(1, 1, 1, 0, NOSTG, NOSTG);
  }

#pragma unroll
  for (int am = 0; am < 8; ++am)
#pragma unroll
    for (int n = 0; n < 4; ++n)
#pragma unroll
      for (int r = 0; r < 4; ++r) {
        long row = rowA0 + (wm << 7) + am * 16 + (g << 2) + r;
        long col = rowB0 + (wn << 6) + n * 16 + ql;
        if (OUTF32) Cf[row * N + col] = acc[am][n][r];
        else        Cb[row * N + col] = f2bf(acc[am][n][r]);
      }
#undef STAGE_A
#undef STAGE_B
#undef PHASE
}

// ---------------- fused K-RoPE (in-place) + V transpose -> vt ----------------
__global__ __launch_bounds__(256) void k_kprep(unsigned short* __restrict__ qkv,
                                               unsigned short* __restrict__ vt,
                                               const float* __restrict__ ct,
                                               const float* __restrict__ st) {
  __shared__ unsigned short lt[64 * 136];
  const int tile = blockIdx.x, h = blockIdx.y;
  const int tid = threadIdx.x;
  const int t0 = tile * 64;
  {
    int row = t0 + (tid >> 2);
    int d0 = (tid & 3) * 32;
    int pos = row & 4095;
    unsigned short* kp = qkv + (long)row * 6144 + 2048 + h * 128 + d0;
    const float* cp = ct + pos * 64 + (d0 >> 1);
    const float* sp = st + pos * 64 + (d0 >> 1);
    f32x4 cv[4], sv[4];
#pragma unroll
    for (int j = 0; j < 4; ++j) { cv[j] = *(const f32x4*)(cp + j * 4); sv[j] = *(const f32x4*)(sp + j * 4); }
    short8v kv[4];
#pragma unroll
    for (int j = 0; j < 4; ++j) kv[j] = *(const short8v*)(kp + j * 8);
#pragma unroll
    for (int j = 0; j < 4; ++j) {
      short8v outv;
#pragma unroll
      for (int p = 0; p < 4; ++p) {
        float a = bf2f((unsigned short)kv[j][2 * p]);
        float b = bf2f((unsigned short)kv[j][2 * p + 1]);
        float c = cv[j][p], s = sv[j][p];
        outv[2 * p]     = (short)f2bf(a * c - b * s);
        outv[2 * p + 1] = (short)f2bf(b * c + a * s);
      }
      *(short8v*)(kp + j * 8) = outv;
    }
  }
  {
    int row = tid >> 2, seg = tid & 3;
    const unsigned short* src = qkv + (long)(t0 + row) * 6144 + 4096 + h * 128 + seg * 32;
#pragma unroll
    for (int j = 0; j < 4; ++j)
      *(short8v*)(lt + row * 136 + seg * 32 + j * 8) = *(const short8v*)(src + j * 8);
  }
  __syncthreads();
  int d = tid >> 1, half = tid & 1;
  int wh = t0 >> 9;
  long dst = ((long)(wh * 16 + h) * 128 + d) * 576 + (t0 & 511) + 16 + half * 32;
  unsigned short tmp[32];
#pragma unroll
  for (int kk = 0; kk < 32; ++kk) tmp[kk] = lt[(half * 32 + kk) * 136 + d];
#pragma unroll
  for (int j = 0; j < 4; ++j) {
    short8v v;
#pragma unroll
    for (int e = 0; e < 8; ++e) v[e] = (short)tmp[j * 8 + e];
    *(short8v*)(vt + dst + j * 8) = v;
  }
}

// ---------------- windowed attention: QBLK=128 (8 waves), KVBLK=32 ----------------------
// grid: (wh=16, h=16, qb=4) — XCD-balanced. 3-buffer K/V pipeline with counted vmcnt
// (T4): raw s_barrier at iter top; stage issued 2 tiles ahead; vmcnt(4) in steady state
// (4->2->0 in epilogue) — prefetch latency covered by ~2 tiles of compute instead of <1.
__global__ __launch_bounds__(512) void k_attn(const unsigned short* __restrict__ qkv,
                                              const unsigned short* __restrict__ vt,
                                              const unsigned short* __restrict__ pmk,
                                              const unsigned short* __restrict__ zbuf,
                                              const float* __restrict__ ct,
                                              const float* __restrict__ stt,
                                              unsigned short* __restrict__ attno) {
  __shared__ __align__(16) unsigned short Ks[3][32 * 128];  // [key][d], src-swizzled
  __shared__ __align__(16) unsigned short Vs[3][128 * 32];  // [d][key], src-swizzled
  __shared__ unsigned Ps[8][16][16];                        // per-wave P^T strip (bf16 pairs)
  const int wh = blockIdx.x, h = blockIdx.y, qb = blockIdx.z;
  const int tid = threadIdx.x;
  const int wave = tid >> 6, lane = tid & 63;
  const int ql = lane & 15, g = lane >> 4;
  const int tokbase = (wh >> 3) * 4096 + (wh & 7) * 512;
  const int qi = qb * 128 + wave * 16 + ql;
  const int wqmin = qb * 128 + wave * 16;
  const int wqmax = wqmin + 15;
  const long qrow = (long)(tokbase + qi) * 6144;
  const int pos = (tokbase + qi) & 4095;
  short8v qf[4];
#pragma unroll
  for (int ks = 0; ks < 4; ++ks) {
    short8v qv = *(const short8v*)(qkv + qrow + h * 128 + ks * 32 + g * 8);
    f32x4 cv = *(const f32x4*)(ct + pos * 64 + ks * 16 + g * 4);
    f32x4 sv = *(const f32x4*)(stt + pos * 64 + ks * 16 + g * 4);
    const float SC = 0.08838834764831845f;
#pragma unroll
    for (int p = 0; p < 4; ++p) {
      float a = bf2f((unsigned short)qv[2 * p]);
      float b = bf2f((unsigned short)qv[2 * p + 1]);
      qf[ks][2 * p]     = (short)f2bf((a * cv[p] - b * sv[p]) * SC);
      qf[ks][2 * p + 1] = (short)f2bf((b * cv[p] + a * sv[p]) * SC);
    }
  }
  const int nkt = min(17, (qb * 128 + 144 + 31) >> 5);  // 5,9,13,17
  const long vbase = (long)(wh * 16 + h) * 128 * 576;

  float mrun = -3.0e38f, lrun = 0.f;  // lrun per-lane partial (reduced at end)
  f32x4 o[8] = {};

#define STAGEKV(kt, b) do { \
    { int kl_ = tid >> 4, dc_ = tid & 15, dcs_ = dc_ ^ (kl_ & 7); \
      int ki_ = (kt) * 32 + kl_; \
      const unsigned short* src_; \
      if (ki_ < 16)       src_ = pmk + (h * 16 + ki_) * 128 + dcs_ * 8; \
      else if (ki_ < 528) src_ = qkv + (long)(tokbase + ki_ - 16) * 6144 + 2048 + h * 128 + dcs_ * 8; \
      else                src_ = zbuf; \
      gload16(src_, &Ks[b][0] + (size_t)tid * 8); } \
    { int d_ = tid >> 2, kc_ = tid & 3, kcs_ = kc_ ^ (d_ & 3); \
      gload16(vt + vbase + (long)d_ * 576 + (kt) * 32 + kcs_ * 8, &Vs[b][0] + (size_t)tid * 8); } \
  } while (0)

  STAGEKV(0, 0);
  STAGEKV(1, 1);
  for (int kt = 0; kt < nkt; ++kt) {
    const int cur = kt % 3;
    // top barrier: separates prior iter's reads from this iter's stage-writes
    SCHEDB; __builtin_amdgcn_s_barrier(); SCHEDB;
    if (kt + 2 < nkt) STAGEKV(kt + 2, (kt + 2) % 3);
    // counted wait: tile kt's loads (issued 2 iters ago) must have landed
    if (kt + 2 < nkt)      VMCNT4;
    else if (kt + 1 < nkt) VMCNT2;
    else                   VMCNT0;
    SCHEDB;
    if (kt * 32 <= wqmax + 16) {  // wave-skip fully-masked tiles
      f32x4 stv[2] = {};
      __builtin_amdgcn_s_setprio(1);
#pragma unroll
      for (int kf = 0; kf < 2; ++kf) {
        int row = kf * 16 + ql;
#pragma unroll
        for (int ks = 0; ks < 4; ++ks) {
          int chunk = (ks * 4 + g) ^ (row & 7);
          short8v kv = *(const short8v*)(&Ks[cur][0] + row * 128 + chunk * 8);
          stv[kf] = __builtin_amdgcn_mfma_f32_16x16x32_bf16(kv, qf[ks], stv[kf], 0, 0, 0);
        }
      }
      __builtin_amdgcn_s_setprio(0);
      float tmax = -3.0e38f;
      const bool needmask = !(kt == 0 || (kt * 32 + 15 <= wqmin));
      if (needmask) {
#pragma unroll
        for (int kf = 0; kf < 2; ++kf)
#pragma unroll
          for (int r = 0; r < 4; ++r) {
            int ki = kt * 32 + kf * 16 + g * 4 + r;
            bool ok = (ki < 32) || (qi >= 16 && ki <= qi + 16);
            float s = ok ? stv[kf][r] : -3.0e38f;
            stv[kf][r] = s;
            tmax = fmaxf(tmax, s);
          }
      } else {
#pragma unroll
        for (int kf = 0; kf < 2; ++kf)
#pragma unroll
          for (int r = 0; r < 4; ++r) tmax = fmaxf(tmax, stv[kf][r]);
      }
      tmax = fmaxf(tmax, __shfl_xor(tmax, 16));
      tmax = fmaxf(tmax, __shfl_xor(tmax, 32));
      if (!__all(tmax <= mrun + 8.f)) {
        float mnew = fmaxf(mrun, tmax);
        float corr = __expf(mrun - mnew);
        lrun *= corr;
#pragma unroll
        for (int db = 0; db < 8; ++db) {
          o[db][0] *= corr; o[db][1] *= corr; o[db][2] *= corr; o[db][3] *= corr;
        }
        mrun = mnew;
      }
#pragma unroll
      for (int kf = 0; kf < 2; ++kf)
#pragma unroll
        for (int r = 0; r < 4; ++r) {
          float p = __expf(stv[kf][r] - mrun);
          stv[kf][r] = p;
          lrun += p;
        }
      // P^T -> bf16 pairs -> wave-local LDS strip -> B-fragment
#pragma unroll
      for (int kf = 0; kf < 2; ++kf) {
        unsigned w01 = (unsigned)f2bf(stv[kf][0]) | ((unsigned)f2bf(stv[kf][1]) << 16);
        unsigned w23 = (unsigned)f2bf(stv[kf][2]) | ((unsigned)f2bf(stv[kf][3]) << 16);
        int pr = kf * 8 + 2 * g;
        Ps[wave][pr][ql ^ (pr & 7)] = w01;
        Ps[wave][pr + 1][ql ^ ((pr + 1) & 7)] = w23;
      }
      u32x4 pbw;
#pragma unroll
      for (int t = 0; t < 4; ++t) {
        int pr = 4 * g + t;
        pbw[t] = Ps[wave][pr][ql ^ (pr & 7)];
      }
      short8v pb = __builtin_bit_cast(short8v, pbw);
      __builtin_amdgcn_s_setprio(1);
#pragma unroll
      for (int db = 0; db < 8; ++db) {
        int d = db * 16 + ql;
        int kc = g ^ (d & 3);
        short8v vf = *(const short8v*)(&Vs[cur][0] + d * 32 + kc * 8);
        o[db] = __builtin_amdgcn_mfma_f32_16x16x32_bf16(vf, pb, o[db], 0, 0, 0);
      }
      __builtin_amdgcn_s_setprio(0);
    }
  }
#undef STAGEKV
  lrun += __shfl_xor(lrun, 16);
  lrun += __shfl_xor(lrun, 32);
  float inv = 1.0f / lrun;
  long obase = (long)(tokbase + qi) * 2048 + h * 128;
#pragma unroll
  for (int db = 0; db < 8; ++db) {
    us4 ov;
#pragma unroll
    for (int r = 0; r < 4; ++r) ov[r] = f2bf(o[db][r] * inv);
    *(us4*)(attno + obase + db * 16 + g * 4) = ov;
  }
}

extern "C" void kernel_launch(void* const* d_in, const int* in_sizes, int n_in,
                              void* d_out, int out_size, void* d_ws, size_t ws_size,
                              hipStream_t stream) {
  const float* x      = (const float*)d_in[0];
  const float* norm_w = (const float*)d_in[1];
  const float* w_qkv  = (const float*)d_in[2];
  const float* w_out  = (const float*)d_in[3];
  const float* pm     = (const float*)d_in[4];
  float* out = (float*)d_out;

  char* ws = (char*)d_ws;
  size_t off = 0;
  auto alloc = [&](size_t bytes) -> void* {
    void* p = ws + off;
    off += (bytes + 255) & ~(size_t)255;
    return p;
  };
  unsigned short* xb    = (unsigned short*)alloc(8192ull * 2048 * 2);
  unsigned short* wqkvb = (unsigned short*)alloc(6144ull * 2048 * 2);
  unsigned short* woutb = (unsigned short*)alloc(2048ull * 2048 * 2);
  unsigned short* qkv   = (unsigned short*)alloc(8192ull * 6144 * 2);
  unsigned short* vt    = (unsigned short*)alloc(256ull * 128 * 576 * 2);
  unsigned short* attno = (unsigned short*)alloc(8192ull * 2048 * 2);
  unsigned short* pmk   = (unsigned short*)alloc(16 * 16 * 128 * 2);
  float* ct             = (float*)alloc(4096 * 64 * 4);
  float* stt            = (float*)alloc(4096 * 64 * 4);
  unsigned short* zbuf  = (unsigned short*)alloc(256);

  hipLaunchKernelGGL(k_prep, dim3(25728), dim3(256), 0, stream,
                     w_qkv, wqkvb, w_out, woutb, pm, pmk, vt, zbuf, ct, stt, x, norm_w, xb);
  hipLaunchKernelGGL((k_gemm8<0>), dim3(24 * 32), dim3(512), 0, stream,
                     xb, wqkvb, qkv, (float*)nullptr, 8192, 6144, 2048);
  hipLaunchKernelGGL(k_kprep, dim3(128, 16), dim3(256), 0, stream, qkv, vt, ct, stt);
  hipLaunchKernelGGL(k_attn, dim3(16, 16, 4), dim3(512), 0, stream,
                     qkv, vt, pmk, zbuf, ct, stt, attno);
  hipLaunchKernelGGL((k_gemm8<1>), dim3(8 * 32), dim3(512), 0, stream,
                     attno, woutb, (unsigned short*)nullptr, out, 8192, 2048, 2048);
}

// Round 13
// 398.598 us; speedup vs baseline: 1.0436x; 1.0084x over previous
//
#include <hip/hip_runtime.h>
#include <hip/hip_bf16.h>

typedef __attribute__((ext_vector_type(8))) short short8v;
typedef __attribute__((ext_vector_type(4))) float f32x4;
typedef __attribute__((ext_vector_type(4))) unsigned short us4;
typedef __attribute__((ext_vector_type(4))) unsigned u32x4;

#define DEV static __device__ __forceinline__

DEV unsigned short f2bf(float f) {
  unsigned u = __builtin_bit_cast(unsigned, f);
  u += 0x7FFFu + ((u >> 16) & 1u);
  return (unsigned short)(u >> 16);
}
DEV float bf2f(unsigned short s) {
  unsigned u = ((unsigned)s) << 16;
  return __builtin_bit_cast(float, u);
}
DEV void gload16(const void* g, void* l) {
  __builtin_amdgcn_global_load_lds((const __attribute__((address_space(1))) void*)g,
                                   (__attribute__((address_space(3))) void*)l, 16, 0, 0);
}

// ============ fused prep: cvt(wqkv) | cvt(wout) | pmprep | ropetab | rms ============
__global__ __launch_bounds__(256) void k_prep(const float* __restrict__ w_qkv,
                                              unsigned short* __restrict__ wqkvb,
                                              const float* __restrict__ w_out,
                                              unsigned short* __restrict__ woutb,
                                              const float* __restrict__ pm,
                                              unsigned short* __restrict__ pmk,
                                              unsigned short* __restrict__ vt,
                                              unsigned short* __restrict__ zbuf,
                                              float* __restrict__ ct,
                                              float* __restrict__ st,
                                              const float* __restrict__ x,
                                              const float* __restrict__ norm_w,
                                              unsigned short* __restrict__ xb) {
  __shared__ float red[4];
  const int b = blockIdx.x, tid = threadIdx.x;
  if (b < 12288) {
    long i = (long)b * 256 + tid;
    f32x4 v = *((const f32x4*)w_qkv + i);
    us4 o;
    o[0] = f2bf(v[0]); o[1] = f2bf(v[1]); o[2] = f2bf(v[2]); o[3] = f2bf(v[3]);
    *((us4*)wqkvb + i) = o;
  } else if (b < 16384) {
    long i = (long)(b - 12288) * 256 + tid;
    f32x4 v = *((const f32x4*)w_out + i);
    us4 o;
    o[0] = f2bf(v[0]); o[1] = f2bf(v[1]); o[2] = f2bf(v[2]); o[3] = f2bf(v[3]);
    *((us4*)woutb + i) = o;
  } else if (b < 16512) {
    int idx = (b - 16384) * 256 + tid;
    if (idx < 8) zbuf[idx] = 0;
    int d = idx & 127, p = (idx >> 7) & 15, h = idx >> 11;
    float kvl = pm[((0 * 16 + h) * 16 + p) * 128 + d];
    float vvl = pm[((1 * 16 + h) * 16 + p) * 128 + d];
    pmk[(h * 16 + p) * 128 + d] = f2bf(kvl);
    unsigned short vb = f2bf(vvl);
    for (int w = 0; w < 16; ++w) {
      long base = ((long)(w * 16 + h) * 128 + d) * 576;
      vt[base + p] = vb;
      vt[base + 528 + p] = 0;
      vt[base + 544 + p] = 0;
      vt[base + 560 + p] = 0;
    }
  } else if (b < 17536) {
    int idx = (b - 16512) * 256 + tid;  // 262144
    int pos = idx >> 6, i = idx & 63;
    float invf = __powf(10000.f, -(float)i * (1.f / 64.f));
    float a = (float)pos * invf;
    ct[idx] = cosf(a);
    st[idx] = sinf(a);
  } else {
    int row = b - 17536;
    const f32x4* xr = (const f32x4*)(x + (long)row * 2048);
    f32x4 v0 = xr[tid * 2], v1 = xr[tid * 2 + 1];
    float ss = v0[0]*v0[0] + v0[1]*v0[1] + v0[2]*v0[2] + v0[3]*v0[3]
             + v1[0]*v1[0] + v1[1]*v1[1] + v1[2]*v1[2] + v1[3]*v1[3];
    ss += __shfl_xor(ss, 1);  ss += __shfl_xor(ss, 2);  ss += __shfl_xor(ss, 4);
    ss += __shfl_xor(ss, 8);  ss += __shfl_xor(ss, 16); ss += __shfl_xor(ss, 32);
    if ((tid & 63) == 0) red[tid >> 6] = ss;
    __syncthreads();
    float tot = red[0] + red[1] + red[2] + red[3];
    float rs = rsqrtf(tot * (1.f / 2048.f) + 1e-6f);
    float xv[8] = {v0[0], v0[1], v0[2], v0[3], v1[0], v1[1], v1[2], v1[3]};
    short8v pack;
#pragma unroll
    for (int j = 0; j < 8; ++j) pack[j] = (short)f2bf(xv[j] * rs * norm_w[tid * 8 + j]);
    *((short8v*)(xb + (long)row * 2048) + tid) = pack;
  }
}

// ================= 256x256 8-phase bf16 GEMM: C[M,N] = A[M,K] * B[N,K]^T =================
// R2-exact staging schedule. NEW: column-chunked XCD swizzle — each XCD owns nbx/8
// B-panels (QKV: 3 MB, outproj: 1 MB -> L2-resident) instead of cycling all panels.

#define VMCNT4 asm volatile("s_waitcnt vmcnt(4)" ::: "memory")
#define VMCNT2 asm volatile("s_waitcnt vmcnt(2)" ::: "memory")
#define VMCNT0 asm volatile("s_waitcnt vmcnt(0)" ::: "memory")
#define SCHEDB __builtin_amdgcn_sched_barrier(0)
#define NOSTG ((void)0)

template <int OUTF32>
__global__ __launch_bounds__(512, 2) void k_gemm8(const unsigned short* __restrict__ A,
                                                  const unsigned short* __restrict__ B,
                                                  unsigned short* __restrict__ Cb,
                                                  float* __restrict__ Cf,
                                                  int M, int N, int K) {
  __shared__ __align__(16) unsigned short lds[4 * 256 * 64];  // buf0:A,B buf1:A,B (64KB each)
  const int tid = threadIdx.x;
  const int lane = tid & 63;
  const int ql = lane & 15, g = lane >> 4;
  const int wid = tid >> 6;
  const int wm = wid >> 2, wn = wid & 3;

  const int nbx = N >> 8;
  const int nwg = gridDim.x;
  int bid = blockIdx.x;
  int bx, by;
  if ((nbx & 7) == 0) {
    // column-chunked: XCD x = bid%8 owns bx in [x*cpx, (x+1)*cpx) -> B-panels L2-resident
    const int cpx = nbx >> 3;
    int x = bid & 7, k = bid >> 3;
    bx = x * cpx + (k % cpx);
    by = k / cpx;
  } else {
    int swz = (bid & 7) * (nwg >> 3) + (bid >> 3);
    by = swz / nbx; bx = swz - by * nbx;
  }
  const long rowA0 = (long)by << 8;
  const long rowB0 = (long)bx << 8;

  const int idx0 = tid, idx1 = 512 + tid;
  const int dr0 = idx0 >> 3, sc0 = (idx0 & 7) ^ (dr0 & 7);
  const int dr1 = idx1 >> 3, sc1 = (idx1 & 7) ^ (dr1 & 7);
  const long halfA = 128L * K;
  const unsigned short* pA0 = A + (rowA0 + dr0) * (long)K + sc0 * 8;
  const unsigned short* pA1 = A + (rowA0 + dr1) * (long)K + sc1 * 8;
  const unsigned short* pB0 = B + (rowB0 + dr0) * (long)K + sc0 * 8;
  const unsigned short* pB1 = B + (rowB0 + dr1) * (long)K + sc1 * 8;

  const int rsw0 = (g ^ (ql & 7)) * 8;
  const int rsw1 = ((4 + g) ^ (ql & 7)) * 8;

  short8v fa[4], fb[2][4];
  f32x4 acc[8][4] = {};

#define STAGE_A(b, h, kk) do { \
  gload16(pA0 + (long)(h) * halfA + (kk), lds + (b) * 32768 + (h) * 8192 + (idx0 << 3)); \
  gload16(pA1 + (long)(h) * halfA + (kk), lds + (b) * 32768 + (h) * 8192 + (idx1 << 3)); } while (0)
#define STAGE_B(b, h, kk) do { \
  gload16(pB0 + (long)(h) * halfA + (kk), lds + (b) * 32768 + 16384 + (h) * 8192 + (idx0 << 3)); \
  gload16(pB1 + (long)(h) * halfA + (kk), lds + (b) * 32768 + 16384 + (h) * 8192 + (idx1 << 3)); } while (0)

#define PHASE(buf, mh, ks, LOADB, STG, VMC) do { \
  { const unsigned short* p_ = lds + (buf) * 32768 + (((wm << 7) + (mh) * 64 + ql) << 6) + ((ks) ? rsw1 : rsw0); \
    _Pragma("unroll") for (int mi_ = 0; mi_ < 4; ++mi_) fa[mi_] = *(const short8v*)(p_ + (mi_ << 10)); } \
  if (LOADB) { const unsigned short* p_ = lds + (buf) * 32768 + 16384 + (((wn << 6) + ql) << 6) + ((ks) ? rsw1 : rsw0); \
    _Pragma("unroll") for (int n_ = 0; n_ < 4; ++n_) fb[ks][n_] = *(const short8v*)(p_ + (n_ << 10)); } \
  STG; \
  SCHEDB; __builtin_amdgcn_s_barrier(); SCHEDB; \
  __builtin_amdgcn_s_setprio(1); \
  _Pragma("unroll") for (int mi_ = 0; mi_ < 4; ++mi_) \
    _Pragma("unroll") for (int n_ = 0; n_ < 4; ++n_) \
      acc[(mh) * 4 + mi_][n_] = __builtin_amdgcn_mfma_f32_16x16x32_bf16(fa[mi_], fb[ks][n_], acc[(mh) * 4 + mi_][n_], 0, 0, 0); \
  __builtin_amdgcn_s_setprio(0); \
  VMC; \
  SCHEDB; __builtin_amdgcn_s_barrier(); SCHEDB; \
} while (0)

  const int NT = K >> 6;
  const int NITER = NT >> 1;

  STAGE_A(0, 0, 0); STAGE_A(0, 1, 0);
  STAGE_B(0, 0, 0); STAGE_B(0, 1, 0);
  STAGE_B(1, 0, 64); STAGE_B(1, 1, 64);
  VMCNT4;
  SCHEDB; __builtin_amdgcn_s_barrier(); SCHEDB;

  for (int i = 0; i < NITER - 1; ++i) {
    const int k1 = (2 * i + 1) << 6;
    const int k2 = (2 * i + 2) << 6;
    const int k3 = (2 * i + 3) << 6;
    PHASE(0, 0, 0, 1, STAGE_A(1, 0, k1), NOSTG);
    PHASE(0, 0, 1, 1, STAGE_A(1, 1, k1), NOSTG);
    PHASE(0, 1, 0, 0, STAGE_B(0, 0, k2), NOSTG);
    PHASE(0, 1, 1, 0, STAGE_B(0, 1, k2), VMCNT4);
    PHASE(1, 0, 0, 1, STAGE_A(0, 0, k2), NOSTG);
    PHASE(1, 0, 1, 1, STAGE_A(0, 1, k2), NOSTG);
    PHASE(1, 1, 0, 0, STAGE_B(1, 0, k3), NOSTG);
    PHASE(1, 1, 1, 0, STAGE_B(1, 1, k3), VMCNT4);
  }
  {
    const int k1 = (NT - 1) << 6;
    PHASE(0, 0, 0, 1, STAGE_A(1, 0, k1), NOSTG);
    PHASE(0, 0, 1, 1, STAGE_A(1, 1, k1), NOSTG);
    PHASE(0, 1, 0, 0, NOSTG, NOSTG);
    PHASE(0, 1, 1, 0, NOSTG, VMCNT0);
    PHASE(1, 0, 0, 1, NOSTG, NOSTG);
    PHASE(1, 0, 1, 1, NOSTG, NOSTG);
    PHASE(1, 1, 0, 0, NOSTG, NOSTG);
    PHASE(1, 1, 1, 0, NOSTG, NOSTG);
  }

#pragma unroll
  for (int am = 0; am < 8; ++am)
#pragma unroll
    for (int n = 0; n < 4; ++n)
#pragma unroll
      for (int r = 0; r < 4; ++r) {
        long row = rowA0 + (wm << 7) + am * 16 + (g << 2) + r;
        long col = rowB0 + (wn << 6) + n * 16 + ql;
        if (OUTF32) Cf[row * N + col] = acc[am][n][r];
        else        Cb[row * N + col] = f2bf(acc[am][n][r]);
      }
#undef STAGE_A
#undef STAGE_B
#undef PHASE
}

// ---------------- fused K-RoPE (in-place) + V transpose -> vt ----------------
__global__ __launch_bounds__(256) void k_kprep(unsigned short* __restrict__ qkv,
                                               unsigned short* __restrict__ vt,
                                               const float* __restrict__ ct,
                                               const float* __restrict__ st) {
  __shared__ unsigned short lt[64 * 136];
  const int tile = blockIdx.x, h = blockIdx.y;
  const int tid = threadIdx.x;
  const int t0 = tile * 64;
  {
    int row = t0 + (tid >> 2);
    int d0 = (tid & 3) * 32;
    int pos = row & 4095;
    unsigned short* kp = qkv + (long)row * 6144 + 2048 + h * 128 + d0;
    const float* cp = ct + pos * 64 + (d0 >> 1);
    const float* sp = st + pos * 64 + (d0 >> 1);
    f32x4 cv[4], sv[4];
#pragma unroll
    for (int j = 0; j < 4; ++j) { cv[j] = *(const f32x4*)(cp + j * 4); sv[j] = *(const f32x4*)(sp + j * 4); }
    short8v kv[4];
#pragma unroll
    for (int j = 0; j < 4; ++j) kv[j] = *(const short8v*)(kp + j * 8);
#pragma unroll
    for (int j = 0; j < 4; ++j) {
      short8v outv;
#pragma unroll
      for (int p = 0; p < 4; ++p) {
        float a = bf2f((unsigned short)kv[j][2 * p]);
        float b = bf2f((unsigned short)kv[j][2 * p + 1]);
        float c = cv[j][p], s = sv[j][p];
        outv[2 * p]     = (short)f2bf(a * c - b * s);
        outv[2 * p + 1] = (short)f2bf(b * c + a * s);
      }
      *(short8v*)(kp + j * 8) = outv;
    }
  }
  {
    int row = tid >> 2, seg = tid & 3;
    const unsigned short* src = qkv + (long)(t0 + row) * 6144 + 4096 + h * 128 + seg * 32;
#pragma unroll
    for (int j = 0; j < 4; ++j)
      *(short8v*)(lt + row * 136 + seg * 32 + j * 8) = *(const short8v*)(src + j * 8);
  }
  __syncthreads();
  int d = tid >> 1, half = tid & 1;
  int wh = t0 >> 9;
  long dst = ((long)(wh * 16 + h) * 128 + d) * 576 + (t0 & 511) + 16 + half * 32;
  unsigned short tmp[32];
#pragma unroll
  for (int kk = 0; kk < 32; ++kk) tmp[kk] = lt[(half * 32 + kk) * 136 + d];
#pragma unroll
  for (int j = 0; j < 4; ++j) {
    short8v v;
#pragma unroll
    for (int e = 0; e < 8; ++e) v[e] = (short)tmp[j * 8 + e];
    *(short8v*)(vt + dst + j * 8) = v;
  }
}

// ---------------- windowed attention: QBLK=128 (8 waves), KVBLK=32 ----------------------
// R12-exact: 3-buffer K/V pipeline with counted vmcnt; XCD-balanced grid (wh,h,qb).
__global__ __launch_bounds__(512) void k_attn(const unsigned short* __restrict__ qkv,
                                              const unsigned short* __restrict__ vt,
                                              const unsigned short* __restrict__ pmk,
                                              const unsigned short* __restrict__ zbuf,
                                              const float* __restrict__ ct,
                                              const float* __restrict__ stt,
                                              unsigned short* __restrict__ attno) {
  __shared__ __align__(16) unsigned short Ks[3][32 * 128];  // [key][d], src-swizzled
  __shared__ __align__(16) unsigned short Vs[3][128 * 32];  // [d][key], src-swizzled
  __shared__ unsigned Ps[8][16][16];                        // per-wave P^T strip (bf16 pairs)
  const int wh = blockIdx.x, h = blockIdx.y, qb = blockIdx.z;
  const int tid = threadIdx.x;
  const int wave = tid >> 6, lane = tid & 63;
  const int ql = lane & 15, g = lane >> 4;
  const int tokbase = (wh >> 3) * 4096 + (wh & 7) * 512;
  const int qi = qb * 128 + wave * 16 + ql;
  const int wqmin = qb * 128 + wave * 16;
  const int wqmax = wqmin + 15;
  const long qrow = (long)(tokbase + qi) * 6144;
  const int pos = (tokbase + qi) & 4095;
  short8v qf[4];
#pragma unroll
  for (int ks = 0; ks < 4; ++ks) {
    short8v qv = *(const short8v*)(qkv + qrow + h * 128 + ks * 32 + g * 8);
    f32x4 cv = *(const f32x4*)(ct + pos * 64 + ks * 16 + g * 4);
    f32x4 sv = *(const f32x4*)(stt + pos * 64 + ks * 16 + g * 4);
    const float SC = 0.08838834764831845f;
#pragma unroll
    for (int p = 0; p < 4; ++p) {
      float a = bf2f((unsigned short)qv[2 * p]);
      float b = bf2f((unsigned short)qv[2 * p + 1]);
      qf[ks][2 * p]     = (short)f2bf((a * cv[p] - b * sv[p]) * SC);
      qf[ks][2 * p + 1] = (short)f2bf((b * cv[p] + a * sv[p]) * SC);
    }
  }
  const int nkt = min(17, (qb * 128 + 144 + 31) >> 5);  // 5,9,13,17
  const long vbase = (long)(wh * 16 + h) * 128 * 576;

  float mrun = -3.0e38f, lrun = 0.f;
  f32x4 o[8] = {};

#define STAGEKV(kt, b) do { \
    { int kl_ = tid >> 4, dc_ = tid & 15, dcs_ = dc_ ^ (kl_ & 7); \
      int ki_ = (kt) * 32 + kl_; \
      const unsigned short* src_; \
      if (ki_ < 16)       src_ = pmk + (h * 16 + ki_) * 128 + dcs_ * 8; \
      else if (ki_ < 528) src_ = qkv + (long)(tokbase + ki_ - 16) * 6144 + 2048 + h * 128 + dcs_ * 8; \
      else                src_ = zbuf; \
      gload16(src_, &Ks[b][0] + (size_t)tid * 8); } \
    { int d_ = tid >> 2, kc_ = tid & 3, kcs_ = kc_ ^ (d_ & 3); \
      gload16(vt + vbase + (long)d_ * 576 + (kt) * 32 + kcs_ * 8, &Vs[b][0] + (size_t)tid * 8); } \
  } while (0)

  STAGEKV(0, 0);
  STAGEKV(1, 1);
  for (int kt = 0; kt < nkt; ++kt) {
    const int cur = kt % 3;
    SCHEDB; __builtin_amdgcn_s_barrier(); SCHEDB;
    if (kt + 2 < nkt) STAGEKV(kt + 2, (kt + 2) % 3);
    if (kt + 2 < nkt)      VMCNT4;
    else if (kt + 1 < nkt) VMCNT2;
    else                   VMCNT0;
    SCHEDB;
    if (kt * 32 <= wqmax + 16) {
      f32x4 stv[2] = {};
      __builtin_amdgcn_s_setprio(1);
#pragma unroll
      for (int kf = 0; kf < 2; ++kf) {
        int row = kf * 16 + ql;
#pragma unroll
        for (int ks = 0; ks < 4; ++ks) {
          int chunk = (ks * 4 + g) ^ (row & 7);
          short8v kv = *(const short8v*)(&Ks[cur][0] + row * 128 + chunk * 8);
          stv[kf] = __builtin_amdgcn_mfma_f32_16x16x32_bf16(kv, qf[ks], stv[kf], 0, 0, 0);
        }
      }
      __builtin_amdgcn_s_setprio(0);
      float tmax = -3.0e38f;
      const bool needmask = !(kt == 0 || (kt * 32 + 15 <= wqmin));
      if (needmask) {
#pragma unroll
        for (int kf = 0; kf < 2; ++kf)
#pragma unroll
          for (int r = 0; r < 4; ++r) {
            int ki = kt * 32 + kf * 16 + g * 4 + r;
            bool ok = (ki < 32) || (qi >= 16 && ki <= qi + 16);
            float s = ok ? stv[kf][r] : -3.0e38f;
            stv[kf][r] = s;
            tmax = fmaxf(tmax, s);
          }
      } else {
#pragma unroll
        for (int kf = 0; kf < 2; ++kf)
#pragma unroll
          for (int r = 0; r < 4; ++r) tmax = fmaxf(tmax, stv[kf][r]);
      }
      tmax = fmaxf(tmax, __shfl_xor(tmax, 16));
      tmax = fmaxf(tmax, __shfl_xor(tmax, 32));
      if (!__all(tmax <= mrun + 8.f)) {
        float mnew = fmaxf(mrun, tmax);
        float corr = __expf(mrun - mnew);
        lrun *= corr;
#pragma unroll
        for (int db = 0; db < 8; ++db) {
          o[db][0] *= corr; o[db][1] *= corr; o[db][2] *= corr; o[db][3] *= corr;
        }
        mrun = mnew;
      }
#pragma unroll
      for (int kf = 0; kf < 2; ++kf)
#pragma unroll
        for (int r = 0; r < 4; ++r) {
          float p = __expf(stv[kf][r] - mrun);
          stv[kf][r] = p;
          lrun += p;
        }
#pragma unroll
      for (int kf = 0; kf < 2; ++kf) {
        unsigned w01 = (unsigned)f2bf(stv[kf][0]) | ((unsigned)f2bf(stv[kf][1]) << 16);
        unsigned w23 = (unsigned)f2bf(stv[kf][2]) | ((unsigned)f2bf(stv[kf][3]) << 16);
        int pr = kf * 8 + 2 * g;
        Ps[wave][pr][ql ^ (pr & 7)] = w01;
        Ps[wave][pr + 1][ql ^ ((pr + 1) & 7)] = w23;
      }
      u32x4 pbw;
#pragma unroll
      for (int t = 0; t < 4; ++t) {
        int pr = 4 * g + t;
        pbw[t] = Ps[wave][pr][ql ^ (pr & 7)];
      }
      short8v pb = __builtin_bit_cast(short8v, pbw);
      __builtin_amdgcn_s_setprio(1);
#pragma unroll
      for (int db = 0; db < 8; ++db) {
        int d = db * 16 + ql;
        int kc = g ^ (d & 3);
        short8v vf = *(const short8v*)(&Vs[cur][0] + d * 32 + kc * 8);
        o[db] = __builtin_amdgcn_mfma_f32_16x16x32_bf16(vf, pb, o[db], 0, 0, 0);
      }
      __builtin_amdgcn_s_setprio(0);
    }
  }
#undef STAGEKV
  lrun += __shfl_xor(lrun, 16);
  lrun += __shfl_xor(lrun, 32);
  float inv = 1.0f / lrun;
  long obase = (long)(tokbase + qi) * 2048 + h * 128;
#pragma unroll
  for (int db = 0; db < 8; ++db) {
    us4 ov;
#pragma unroll
    for (int r = 0; r < 4; ++r) ov[r] = f2bf(o[db][r] * inv);
    *(us4*)(attno + obase + db * 16 + g * 4) = ov;
  }
}

extern "C" void kernel_launch(void* const* d_in, const int* in_sizes, int n_in,
                              void* d_out, int out_size, void* d_ws, size_t ws_size,
                              hipStream_t stream) {
  const float* x      = (const float*)d_in[0];
  const float* norm_w = (const float*)d_in[1];
  const float* w_qkv  = (const float*)d_in[2];
  const float* w_out  = (const float*)d_in[3];
  const float* pm     = (const float*)d_in[4];
  float* out = (float*)d_out;

  char* ws = (char*)d_ws;
  size_t off = 0;
  auto alloc = [&](size_t bytes) -> void* {
    void* p = ws + off;
    off += (bytes + 255) & ~(size_t)255;
    return p;
  };
  unsigned short* xb    = (unsigned short*)alloc(8192ull * 2048 * 2);
  unsigned short* wqkvb = (unsigned short*)alloc(6144ull * 2048 * 2);
  unsigned short* woutb = (unsigned short*)alloc(2048ull * 2048 * 2);
  unsigned short* qkv   = (unsigned short*)alloc(8192ull * 6144 * 2);
  unsigned short* vt    = (unsigned short*)alloc(256ull * 128 * 576 * 2);
  unsigned short* attno = (unsigned short*)alloc(8192ull * 2048 * 2);
  unsigned short* pmk   = (unsigned short*)alloc(16 * 16 * 128 * 2);
  float* ct             = (float*)alloc(4096 * 64 * 4);
  float* stt            = (float*)alloc(4096 * 64 * 4);
  unsigned short* zbuf  = (unsigned short*)alloc(256);

  hipLaunchKernelGGL(k_prep, dim3(25728), dim3(256), 0, stream,
                     w_qkv, wqkvb, w_out, woutb, pm, pmk, vt, zbuf, ct, stt, x, norm_w, xb);
  hipLaunchKernelGGL((k_gemm8<0>), dim3(24 * 32), dim3(512), 0, stream,
                     xb, wqkvb, qkv, (float*)nullptr, 8192, 6144, 2048);
  hipLaunchKernelGGL(k_kprep, dim3(128, 16), dim3(256), 0, stream, qkv, vt, ct, stt);
  hipLaunchKernelGGL(k_attn, dim3(16, 16, 4), dim3(512), 0, stream,
                     qkv, vt, pmk, zbuf, ct, stt, attno);
  hipLaunchKernelGGL((k_gemm8<1>), dim3(8 * 32), dim3(512), 0, stream,
                     attno, woutb, (unsigned short*)nullptr, out, 8192, 2048, 2048);
}

// Round 14
// 395.087 us; speedup vs baseline: 1.0528x; 1.0089x over previous
//
#include <hip/hip_runtime.h>
#include <hip/hip_bf16.h>

typedef __attribute__((ext_vector_type(8))) short short8v;
typedef __attribute__((ext_vector_type(4))) float f32x4;
typedef __attribute__((ext_vector_type(4))) unsigned short us4;
typedef __attribute__((ext_vector_type(4))) unsigned u32x4;

#define DEV static __device__ __forceinline__

DEV unsigned short f2bf(float f) {
  unsigned u = __builtin_bit_cast(unsigned, f);
  u += 0x7FFFu + ((u >> 16) & 1u);
  return (unsigned short)(u >> 16);
}
DEV float bf2f(unsigned short s) {
  unsigned u = ((unsigned)s) << 16;
  return __builtin_bit_cast(float, u);
}
DEV void gload16(const void* g, void* l) {
  __builtin_amdgcn_global_load_lds((const __attribute__((address_space(1))) void*)g,
                                   (__attribute__((address_space(3))) void*)l, 16, 0, 0);
}

// ============ fused prep: cvt(wqkv) | cvt(wout) | pmprep | ropetab | rms ============
__global__ __launch_bounds__(256) void k_prep(const float* __restrict__ w_qkv,
                                              unsigned short* __restrict__ wqkvb,
                                              const float* __restrict__ w_out,
                                              unsigned short* __restrict__ woutb,
                                              const float* __restrict__ pm,
                                              unsigned short* __restrict__ pmk,
                                              unsigned short* __restrict__ vt,
                                              unsigned short* __restrict__ zbuf,
                                              float* __restrict__ ct,
                                              float* __restrict__ st,
                                              const float* __restrict__ x,
                                              const float* __restrict__ norm_w,
                                              unsigned short* __restrict__ xb) {
  __shared__ float red[4];
  const int b = blockIdx.x, tid = threadIdx.x;
  if (b < 12288) {
    long i = (long)b * 256 + tid;
    f32x4 v = *((const f32x4*)w_qkv + i);
    us4 o;
    o[0] = f2bf(v[0]); o[1] = f2bf(v[1]); o[2] = f2bf(v[2]); o[3] = f2bf(v[3]);
    *((us4*)wqkvb + i) = o;
  } else if (b < 16384) {
    long i = (long)(b - 12288) * 256 + tid;
    f32x4 v = *((const f32x4*)w_out + i);
    us4 o;
    o[0] = f2bf(v[0]); o[1] = f2bf(v[1]); o[2] = f2bf(v[2]); o[3] = f2bf(v[3]);
    *((us4*)woutb + i) = o;
  } else if (b < 16512) {
    int idx = (b - 16384) * 256 + tid;
    if (idx < 8) zbuf[idx] = 0;
    int d = idx & 127, p = (idx >> 7) & 15, h = idx >> 11;
    float kvl = pm[((0 * 16 + h) * 16 + p) * 128 + d];
    float vvl = pm[((1 * 16 + h) * 16 + p) * 128 + d];
    pmk[(h * 16 + p) * 128 + d] = f2bf(kvl);
    unsigned short vb = f2bf(vvl);
    for (int w = 0; w < 16; ++w) {
      long base = ((long)(w * 16 + h) * 128 + d) * 576;
      vt[base + p] = vb;
      vt[base + 528 + p] = 0;
      vt[base + 544 + p] = 0;
      vt[base + 560 + p] = 0;
    }
  } else if (b < 17536) {
    int idx = (b - 16512) * 256 + tid;  // 262144
    int pos = idx >> 6, i = idx & 63;
    float invf = __powf(10000.f, -(float)i * (1.f / 64.f));
    float a = (float)pos * invf;
    ct[idx] = cosf(a);
    st[idx] = sinf(a);
  } else {
    int row = b - 17536;
    const f32x4* xr = (const f32x4*)(x + (long)row * 2048);
    f32x4 v0 = xr[tid * 2], v1 = xr[tid * 2 + 1];
    float ss = v0[0]*v0[0] + v0[1]*v0[1] + v0[2]*v0[2] + v0[3]*v0[3]
             + v1[0]*v1[0] + v1[1]*v1[1] + v1[2]*v1[2] + v1[3]*v1[3];
    ss += __shfl_xor(ss, 1);  ss += __shfl_xor(ss, 2);  ss += __shfl_xor(ss, 4);
    ss += __shfl_xor(ss, 8);  ss += __shfl_xor(ss, 16); ss += __shfl_xor(ss, 32);
    if ((tid & 63) == 0) red[tid >> 6] = ss;
    __syncthreads();
    float tot = red[0] + red[1] + red[2] + red[3];
    float rs = rsqrtf(tot * (1.f / 2048.f) + 1e-6f);
    float xv[8] = {v0[0], v0[1], v0[2], v0[3], v1[0], v1[1], v1[2], v1[3]};
    short8v pack;
#pragma unroll
    for (int j = 0; j < 8; ++j) pack[j] = (short)f2bf(xv[j] * rs * norm_w[tid * 8 + j]);
    *((short8v*)(xb + (long)row * 2048) + tid) = pack;
  }
}

// ================= 256x256 8-phase bf16 GEMM: C[M,N] = A[M,K] * B[N,K]^T =================
// R13 + fragment-read software pipelining: phase p's MFMA region also issues phase p+1's
// ds_reads into a second frag set (LDS pipe overlaps MFMA pipe instead of lockstep
// serializing). ph1/ph5 remain serial (cross-buffer barrier boundary). Column-chunked
// XCD swizzle retained (FETCH -45%).

#define VMCNT4 asm volatile("s_waitcnt vmcnt(4)" ::: "memory")
#define VMCNT2 asm volatile("s_waitcnt vmcnt(2)" ::: "memory")
#define VMCNT0 asm volatile("s_waitcnt vmcnt(0)" ::: "memory")
#define SCHEDB __builtin_amdgcn_sched_barrier(0)
#define NOSTG ((void)0)
#define BAR SCHEDB; __builtin_amdgcn_s_barrier(); SCHEDB

template <int OUTF32>
__global__ __launch_bounds__(512, 2) void k_gemm8(const unsigned short* __restrict__ A,
                                                  const unsigned short* __restrict__ B,
                                                  unsigned short* __restrict__ Cb,
                                                  float* __restrict__ Cf,
                                                  int M, int N, int K) {
  __shared__ __align__(16) unsigned short lds[4 * 256 * 64];  // buf0:A,B buf1:A,B (32KB each)
  const int tid = threadIdx.x;
  const int lane = tid & 63;
  const int ql = lane & 15, g = lane >> 4;
  const int wid = tid >> 6;
  const int wm = wid >> 2, wn = wid & 3;

  const int nbx = N >> 8;
  const int nwg = gridDim.x;
  int bid = blockIdx.x;
  int bx, by;
  if ((nbx & 7) == 0) {
    const int cpx = nbx >> 3;
    int x = bid & 7, k = bid >> 3;
    bx = x * cpx + (k % cpx);
    by = k / cpx;
  } else {
    int swz = (bid & 7) * (nwg >> 3) + (bid >> 3);
    by = swz / nbx; bx = swz - by * nbx;
  }
  const long rowA0 = (long)by << 8;
  const long rowB0 = (long)bx << 8;

  const int idx0 = tid, idx1 = 512 + tid;
  const int dr0 = idx0 >> 3, sc0 = (idx0 & 7) ^ (dr0 & 7);
  const int dr1 = idx1 >> 3, sc1 = (idx1 & 7) ^ (dr1 & 7);
  const long halfA = 128L * K;
  const unsigned short* pA0 = A + (rowA0 + dr0) * (long)K + sc0 * 8;
  const unsigned short* pA1 = A + (rowA0 + dr1) * (long)K + sc1 * 8;
  const unsigned short* pB0 = B + (rowB0 + dr0) * (long)K + sc0 * 8;
  const unsigned short* pB1 = B + (rowB0 + dr1) * (long)K + sc1 * 8;

  const int rsw0 = (g ^ (ql & 7)) * 8;
  const int rsw1 = ((4 + g) ^ (ql & 7)) * 8;

  short8v faA[4], faB[4], fb[2][4];
  f32x4 acc[8][4] = {};

#define STAGE_A(b, h, kk) do { \
  gload16(pA0 + (long)(h) * halfA + (kk), lds + (b) * 32768 + (h) * 8192 + (idx0 << 3)); \
  gload16(pA1 + (long)(h) * halfA + (kk), lds + (b) * 32768 + (h) * 8192 + (idx1 << 3)); } while (0)
#define STAGE_B(b, h, kk) do { \
  gload16(pB0 + (long)(h) * halfA + (kk), lds + (b) * 32768 + 16384 + (h) * 8192 + (idx0 << 3)); \
  gload16(pB1 + (long)(h) * halfA + (kk), lds + (b) * 32768 + 16384 + (h) * 8192 + (idx1 << 3)); } while (0)

#define RD_FA(dst, buf, mh, ks) do { \
  const unsigned short* p_ = lds + (buf) * 32768 + (((wm << 7) + (mh) * 64 + ql) << 6) + ((ks) ? rsw1 : rsw0); \
  _Pragma("unroll") for (int mi_ = 0; mi_ < 4; ++mi_) dst[mi_] = *(const short8v*)(p_ + (mi_ << 10)); \
} while (0)
#define RD_FB(buf, ks) do { \
  const unsigned short* p_ = lds + (buf) * 32768 + 16384 + (((wn << 6) + ql) << 6) + ((ks) ? rsw1 : rsw0); \
  _Pragma("unroll") for (int n_ = 0; n_ < 4; ++n_) fb[ks][n_] = *(const short8v*)(p_ + (n_ << 10)); \
} while (0)
#define MM(mh, ks, src) do { \
  _Pragma("unroll") for (int mi_ = 0; mi_ < 4; ++mi_) \
    _Pragma("unroll") for (int n_ = 0; n_ < 4; ++n_) \
      acc[(mh) * 4 + mi_][n_] = __builtin_amdgcn_mfma_f32_16x16x32_bf16(src[mi_], fb[ks][n_], acc[(mh) * 4 + mi_][n_], 0, 0, 0); \
} while (0)

// phase skeleton: STG; mid-barrier; [prefetch p+1 reads || MFMA p]; VMC; closing barrier
#define PH(STG_, PRE_, MM_, VMC_) do { \
  STG_; \
  BAR; \
  __builtin_amdgcn_s_setprio(1); \
  PRE_; \
  MM_; \
  __builtin_amdgcn_s_setprio(0); \
  VMC_; \
  BAR; \
} while (0)

  const int NT = K >> 6;
  const int NITER = NT >> 1;

  STAGE_A(0, 0, 0); STAGE_A(0, 1, 0);
  STAGE_B(0, 0, 0); STAGE_B(0, 1, 0);
  STAGE_B(1, 0, 64); STAGE_B(1, 1, 64);
  VMCNT4;
  BAR;

  for (int i = 0; i < NITER - 1; ++i) {
    const int k1 = (2 * i + 1) << 6;
    const int k2 = (2 * i + 2) << 6;
    const int k3 = (2 * i + 3) << 6;
    // ph1 (serial reads: buf0 valid since prior closing barrier)
    RD_FA(faA, 0, 0, 0); RD_FB(0, 0);
    PH(STAGE_A(1, 0, k1), { RD_FA(faB, 0, 0, 1); RD_FB(0, 1); }, MM(0, 0, faA), NOSTG);
    // ph2
    PH(STAGE_A(1, 1, k1), { RD_FA(faA, 0, 1, 0); },             MM(0, 1, faB), NOSTG);
    // ph3
    PH(STAGE_B(0, 0, k2), { RD_FA(faB, 0, 1, 1); },             MM(1, 0, faA), NOSTG);
    // ph4
    PH(STAGE_B(0, 1, k2), {},                                   MM(1, 1, faB), VMCNT4);
    // ph5 (serial reads: buf1 valid after ph4 vmcnt+barrier)
    RD_FA(faA, 1, 0, 0); RD_FB(1, 0);
    PH(STAGE_A(0, 0, k2), { RD_FA(faB, 1, 0, 1); RD_FB(1, 1); }, MM(0, 0, faA), NOSTG);
    // ph6
    PH(STAGE_A(0, 1, k2), { RD_FA(faA, 1, 1, 0); },             MM(0, 1, faB), NOSTG);
    // ph7
    PH(STAGE_B(1, 0, k3), { RD_FA(faB, 1, 1, 1); },             MM(1, 0, faA), NOSTG);
    // ph8
    PH(STAGE_B(1, 1, k3), {},                                   MM(1, 1, faB), VMCNT4);
  }
  {  // epilogue: tiles NT-2 (buf0), NT-1 (buf1)
    const int k1 = (NT - 1) << 6;
    RD_FA(faA, 0, 0, 0); RD_FB(0, 0);
    PH(STAGE_A(1, 0, k1), { RD_FA(faB, 0, 0, 1); RD_FB(0, 1); }, MM(0, 0, faA), NOSTG);
    PH(STAGE_A(1, 1, k1), { RD_FA(faA, 0, 1, 0); },             MM(0, 1, faB), NOSTG);
    PH(NOSTG,             { RD_FA(faB, 0, 1, 1); },             MM(1, 0, faA), NOSTG);
    PH(NOSTG,             {},                                   MM(1, 1, faB), VMCNT0);
    RD_FA(faA, 1, 0, 0); RD_FB(1, 0);
    PH(NOSTG,             { RD_FA(faB, 1, 0, 1); RD_FB(1, 1); }, MM(0, 0, faA), NOSTG);
    PH(NOSTG,             { RD_FA(faA, 1, 1, 0); },             MM(0, 1, faB), NOSTG);
    PH(NOSTG,             { RD_FA(faB, 1, 1, 1); },             MM(1, 0, faA), NOSTG);
    PH(NOSTG,             {},                                   MM(1, 1, faB), NOSTG);
  }

#pragma unroll
  for (int am = 0; am < 8; ++am)
#pragma unroll
    for (int n = 0; n < 4; ++n)
#pragma unroll
      for (int r = 0; r < 4; ++r) {
        long row = rowA0 + (wm << 7) + am * 16 + (g << 2) + r;
        long col = rowB0 + (wn << 6) + n * 16 + ql;
        if (OUTF32) Cf[row * N + col] = acc[am][n][r];
        else        Cb[row * N + col] = f2bf(acc[am][n][r]);
      }
#undef STAGE_A
#undef STAGE_B
#undef RD_FA
#undef RD_FB
#undef MM
#undef PH
}

// ---------------- fused K-RoPE (in-place) + V transpose -> vt ----------------
__global__ __launch_bounds__(256) void k_kprep(unsigned short* __restrict__ qkv,
                                               unsigned short* __restrict__ vt,
                                               const float* __restrict__ ct,
                                               const float* __restrict__ st) {
  __shared__ unsigned short lt[64 * 136];
  const int tile = blockIdx.x, h = blockIdx.y;
  const int tid = threadIdx.x;
  const int t0 = tile * 64;
  {
    int row = t0 + (tid >> 2);
    int d0 = (tid & 3) * 32;
    int pos = row & 4095;
    unsigned short* kp = qkv + (long)row * 6144 + 2048 + h * 128 + d0;
    const float* cp = ct + pos * 64 + (d0 >> 1);
    const float* sp = st + pos * 64 + (d0 >> 1);
    f32x4 cv[4], sv[4];
#pragma unroll
    for (int j = 0; j < 4; ++j) { cv[j] = *(const f32x4*)(cp + j * 4); sv[j] = *(const f32x4*)(sp + j * 4); }
    short8v kv[4];
#pragma unroll
    for (int j = 0; j < 4; ++j) kv[j] = *(const short8v*)(kp + j * 8);
#pragma unroll
    for (int j = 0; j < 4; ++j) {
      short8v outv;
#pragma unroll
      for (int p = 0; p < 4; ++p) {
        float a = bf2f((unsigned short)kv[j][2 * p]);
        float b = bf2f((unsigned short)kv[j][2 * p + 1]);
        float c = cv[j][p], s = sv[j][p];
        outv[2 * p]     = (short)f2bf(a * c - b * s);
        outv[2 * p + 1] = (short)f2bf(b * c + a * s);
      }
      *(short8v*)(kp + j * 8) = outv;
    }
  }
  {
    int row = tid >> 2, seg = tid & 3;
    const unsigned short* src = qkv + (long)(t0 + row) * 6144 + 4096 + h * 128 + seg * 32;
#pragma unroll
    for (int j = 0; j < 4; ++j)
      *(short8v*)(lt + row * 136 + seg * 32 + j * 8) = *(const short8v*)(src + j * 8);
  }
  __syncthreads();
  int d = tid >> 1, half = tid & 1;
  int wh = t0 >> 9;
  long dst = ((long)(wh * 16 + h) * 128 + d) * 576 + (t0 & 511) + 16 + half * 32;
  unsigned short tmp[32];
#pragma unroll
  for (int kk = 0; kk < 32; ++kk) tmp[kk] = lt[(half * 32 + kk) * 136 + d];
#pragma unroll
  for (int j = 0; j < 4; ++j) {
    short8v v;
#pragma unroll
    for (int e = 0; e < 8; ++e) v[e] = (short)tmp[j * 8 + e];
    *(short8v*)(vt + dst + j * 8) = v;
  }
}

// ---------------- windowed attention: QBLK=128 (8 waves), KVBLK=32 ----------------------
// R12-exact: 3-buffer K/V pipeline with counted vmcnt; XCD-balanced grid (wh,h,qb).
__global__ __launch_bounds__(512) void k_attn(const unsigned short* __restrict__ qkv,
                                              const unsigned short* __restrict__ vt,
                                              const unsigned short* __restrict__ pmk,
                                              const unsigned short* __restrict__ zbuf,
                                              const float* __restrict__ ct,
                                              const float* __restrict__ stt,
                                              unsigned short* __restrict__ attno) {
  __shared__ __align__(16) unsigned short Ks[3][32 * 128];  // [key][d], src-swizzled
  __shared__ __align__(16) unsigned short Vs[3][128 * 32];  // [d][key], src-swizzled
  __shared__ unsigned Ps[8][16][16];                        // per-wave P^T strip (bf16 pairs)
  const int wh = blockIdx.x, h = blockIdx.y, qb = blockIdx.z;
  const int tid = threadIdx.x;
  const int wave = tid >> 6, lane = tid & 63;
  const int ql = lane & 15, g = lane >> 4;
  const int tokbase = (wh >> 3) * 4096 + (wh & 7) * 512;
  const int qi = qb * 128 + wave * 16 + ql;
  const int wqmin = qb * 128 + wave * 16;
  const int wqmax = wqmin + 15;
  const long qrow = (long)(tokbase + qi) * 6144;
  const int pos = (tokbase + qi) & 4095;
  short8v qf[4];
#pragma unroll
  for (int ks = 0; ks < 4; ++ks) {
    short8v qv = *(const short8v*)(qkv + qrow + h * 128 + ks * 32 + g * 8);
    f32x4 cv = *(const f32x4*)(ct + pos * 64 + ks * 16 + g * 4);
    f32x4 sv = *(const f32x4*)(stt + pos * 64 + ks * 16 + g * 4);
    const float SC = 0.08838834764831845f;
#pragma unroll
    for (int p = 0; p < 4; ++p) {
      float a = bf2f((unsigned short)qv[2 * p]);
      float b = bf2f((unsigned short)qv[2 * p + 1]);
      qf[ks][2 * p]     = (short)f2bf((a * cv[p] - b * sv[p]) * SC);
      qf[ks][2 * p + 1] = (short)f2bf((b * cv[p] + a * sv[p]) * SC);
    }
  }
  const int nkt = min(17, (qb * 128 + 144 + 31) >> 5);  // 5,9,13,17
  const long vbase = (long)(wh * 16 + h) * 128 * 576;

  float mrun = -3.0e38f, lrun = 0.f;
  f32x4 o[8] = {};

#define STAGEKV(kt, b) do { \
    { int kl_ = tid >> 4, dc_ = tid & 15, dcs_ = dc_ ^ (kl_ & 7); \
      int ki_ = (kt) * 32 + kl_; \
      const unsigned short* src_; \
      if (ki_ < 16)       src_ = pmk + (h * 16 + ki_) * 128 + dcs_ * 8; \
      else if (ki_ < 528) src_ = qkv + (long)(tokbase + ki_ - 16) * 6144 + 2048 + h * 128 + dcs_ * 8; \
      else                src_ = zbuf; \
      gload16(src_, &Ks[b][0] + (size_t)tid * 8); } \
    { int d_ = tid >> 2, kc_ = tid & 3, kcs_ = kc_ ^ (d_ & 3); \
      gload16(vt + vbase + (long)d_ * 576 + (kt) * 32 + kcs_ * 8, &Vs[b][0] + (size_t)tid * 8); } \
  } while (0)

  STAGEKV(0, 0);
  STAGEKV(1, 1);
  for (int kt = 0; kt < nkt; ++kt) {
    const int cur = kt % 3;
    SCHEDB; __builtin_amdgcn_s_barrier(); SCHEDB;
    if (kt + 2 < nkt) STAGEKV(kt + 2, (kt + 2) % 3);
    if (kt + 2 < nkt)      VMCNT4;
    else if (kt + 1 < nkt) VMCNT2;
    else                   VMCNT0;
    SCHEDB;
    if (kt * 32 <= wqmax + 16) {
      f32x4 stv[2] = {};
      __builtin_amdgcn_s_setprio(1);
#pragma unroll
      for (int kf = 0; kf < 2; ++kf) {
        int row = kf * 16 + ql;
#pragma unroll
        for (int ks = 0; ks < 4; ++ks) {
          int chunk = (ks * 4 + g) ^ (row & 7);
          short8v kv = *(const short8v*)(&Ks[cur][0] + row * 128 + chunk * 8);
          stv[kf] = __builtin_amdgcn_mfma_f32_16x16x32_bf16(kv, qf[ks], stv[kf], 0, 0, 0);
        }
      }
      __builtin_amdgcn_s_setprio(0);
      float tmax = -3.0e38f;
      const bool needmask = !(kt == 0 || (kt * 32 + 15 <= wqmin));
      if (needmask) {
#pragma unroll
        for (int kf = 0; kf < 2; ++kf)
#pragma unroll
          for (int r = 0; r < 4; ++r) {
            int ki = kt * 32 + kf * 16 + g * 4 + r;
            bool ok = (ki < 32) || (qi >= 16 && ki <= qi + 16);
            float s = ok ? stv[kf][r] : -3.0e38f;
            stv[kf][r] = s;
            tmax = fmaxf(tmax, s);
          }
      } else {
#pragma unroll
        for (int kf = 0; kf < 2; ++kf)
#pragma unroll
          for (int r = 0; r < 4; ++r) tmax = fmaxf(tmax, stv[kf][r]);
      }
      tmax = fmaxf(tmax, __shfl_xor(tmax, 16));
      tmax = fmaxf(tmax, __shfl_xor(tmax, 32));
      if (!__all(tmax <= mrun + 8.f)) {
        float mnew = fmaxf(mrun, tmax);
        float corr = __expf(mrun - mnew);
        lrun *= corr;
#pragma unroll
        for (int db = 0; db < 8; ++db) {
          o[db][0] *= corr; o[db][1] *= corr; o[db][2] *= corr; o[db][3] *= corr;
        }
        mrun = mnew;
      }
#pragma unroll
      for (int kf = 0; kf < 2; ++kf)
#pragma unroll
        for (int r = 0; r < 4; ++r) {
          float p = __expf(stv[kf][r] - mrun);
          stv[kf][r] = p;
          lrun += p;
        }
#pragma unroll
      for (int kf = 0; kf < 2; ++kf) {
        unsigned w01 = (unsigned)f2bf(stv[kf][0]) | ((unsigned)f2bf(stv[kf][1]) << 16);
        unsigned w23 = (unsigned)f2bf(stv[kf][2]) | ((unsigned)f2bf(stv[kf][3]) << 16);
        int pr = kf * 8 + 2 * g;
        Ps[wave][pr][ql ^ (pr & 7)] = w01;
        Ps[wave][pr + 1][ql ^ ((pr + 1) & 7)] = w23;
      }
      u32x4 pbw;
#pragma unroll
      for (int t = 0; t < 4; ++t) {
        int pr = 4 * g + t;
        pbw[t] = Ps[wave][pr][ql ^ (pr & 7)];
      }
      short8v pb = __builtin_bit_cast(short8v, pbw);
      __builtin_amdgcn_s_setprio(1);
#pragma unroll
      for (int db = 0; db < 8; ++db) {
        int d = db * 16 + ql;
        int kc = g ^ (d & 3);
        short8v vf = *(const short8v*)(&Vs[cur][0] + d * 32 + kc * 8);
        o[db] = __builtin_amdgcn_mfma_f32_16x16x32_bf16(vf, pb, o[db], 0, 0, 0);
      }
      __builtin_amdgcn_s_setprio(0);
    }
  }
#undef STAGEKV
  lrun += __shfl_xor(lrun, 16);
  lrun += __shfl_xor(lrun, 32);
  float inv = 1.0f / lrun;
  long obase = (long)(tokbase + qi) * 2048 + h * 128;
#pragma unroll
  for (int db = 0; db < 8; ++db) {
    us4 ov;
#pragma unroll
    for (int r = 0; r < 4; ++r) ov[r] = f2bf(o[db][r] * inv);
    *(us4*)(attno + obase + db * 16 + g * 4) = ov;
  }
}

extern "C" void kernel_launch(void* const* d_in, const int* in_sizes, int n_in,
                              void* d_out, int out_size, void* d_ws, size_t ws_size,
                              hipStream_t stream) {
  const float* x      = (const float*)d_in[0];
  const float* norm_w = (const float*)d_in[1];
  const float* w_qkv  = (const float*)d_in[2];
  const float* w_out  = (const float*)d_in[3];
  const float* pm     = (const float*)d_in[4];
  float* out = (float*)d_out;

  char* ws = (char*)d_ws;
  size_t off = 0;
  auto alloc = [&](size_t bytes) -> void* {
    void* p = ws + off;
    off += (bytes + 255) & ~(size_t)255;
    return p;
  };
  unsigned short* xb    = (unsigned short*)alloc(8192ull * 2048 * 2);
  unsigned short* wqkvb = (unsigned short*)alloc(6144ull * 2048 * 2);
  unsigned short* woutb = (unsigned short*)alloc(2048ull * 2048 * 2);
  unsigned short* qkv   = (unsigned short*)alloc(8192ull * 6144 * 2);
  unsigned short* vt    = (unsigned short*)alloc(256ull * 128 * 576 * 2);
  unsigned short* attno = (unsigned short*)alloc(8192ull * 2048 * 2);
  unsigned short* pmk   = (unsigned short*)alloc(16 * 16 * 128 * 2);
  float* ct             = (float*)alloc(4096 * 64 * 4);
  float* stt            = (float*)alloc(4096 * 64 * 4);
  unsigned short* zbuf  = (unsigned short*)alloc(256);

  hipLaunchKernelGGL(k_prep, dim3(25728), dim3(256), 0, stream,
                     w_qkv, wqkvb, w_out, woutb, pm, pmk, vt, zbuf, ct, stt, x, norm_w, xb);
  hipLaunchKernelGGL((k_gemm8<0>), dim3(24 * 32), dim3(512), 0, stream,
                     xb, wqkvb, qkv, (float*)nullptr, 8192, 6144, 2048);
  hipLaunchKernelGGL(k_kprep, dim3(128, 16), dim3(256), 0, stream, qkv, vt, ct, stt);
  hipLaunchKernelGGL(k_attn, dim3(16, 16, 4), dim3(512), 0, stream,
                     qkv, vt, pmk, zbuf, ct, stt, attno);
  hipLaunchKernelGGL((k_gemm8<1>), dim3(8 * 32), dim3(512), 0, stream,
                     attno, woutb, (unsigned short*)nullptr, out, 8192, 2048, 2048);
}